// Round 1
// baseline (4730.676 us; speedup 1.0000x reference)
//
#include <hip/hip_runtime.h>
#include <hip/hip_bf16.h>
#include <math.h>

// ---- problem constants ----
// bs=32, S=512, D=256, HS=4 heads (head dim = D = 256!), NT = 16384 tokens
// patch: NP=16 patches x P=16, CC=128, HP=4 heads x CE=32

__device__ __forceinline__ float bf_lo(unsigned u){ return __uint_as_float(u << 16); }
__device__ __forceinline__ float bf_hi(unsigned u){ return __uint_as_float(u & 0xFFFF0000u); }
__device__ __forceinline__ unsigned short f2bf(float f){
  unsigned u = __float_as_uint(f);
  return (unsigned short)((u + 0x7FFFu + ((u >> 16) & 1u)) >> 16);   // RNE
}

// ---------------------------------------------------------------------------
// prep: WqkvT[k][j] (k<256, j<3072) = concat(Wq,Wk,Wv)[j][k]
// ---------------------------------------------------------------------------
__global__ __launch_bounds__(256) void k_prep(const float* __restrict__ Wq,
                                              const float* __restrict__ Wk,
                                              const float* __restrict__ Wv,
                                              float* __restrict__ WqkvT)
{
  int idx = blockIdx.x * 256 + threadIdx.x;       // 786432 total
  int k = idx / 3072, j = idx - k * 3072;
  const float* W = (j < 1024) ? Wq : (j < 2048 ? Wk : Wv);
  int jj = j & 1023;
  WqkvT[idx] = W[jj * 256 + k];
}

// ---------------------------------------------------------------------------
// K1: QKV projection. block = 16 tokens, 256 threads; thread owns 4 output
// cols; writes bf16 Q/K/V in [bh][s][d] layout.
// ---------------------------------------------------------------------------
__global__ __launch_bounds__(256) void k_qkv(const float* __restrict__ x,
                                             const float* __restrict__ WqkvT,
                                             const float* __restrict__ bq,
                                             const float* __restrict__ bk,
                                             const float* __restrict__ bv,
                                             unsigned short* __restrict__ Qw,
                                             unsigned short* __restrict__ Kw,
                                             unsigned short* __restrict__ Vw)
{
  __shared__ float xs[256][16];          // [k][t]
  const int tid = threadIdx.x;
  const int n0  = blockIdx.x << 4;
  for (int i = tid; i < 4096; i += 256){
    int t = i >> 8, k = i & 255;
    xs[k][t] = x[(n0 + t) * 256 + k];
  }
  __syncthreads();

  const int h  = tid >> 6;               // head of this thread's 4 cols
  const int d  = (tid << 2) & 255;
  const int jj = tid << 2;               // col within the 1024-wide matrix

  #pragma unroll 1
  for (int chunk = 0; chunk < 3; ++chunk){
    const float* bb = (chunk == 0) ? bq : (chunk == 1 ? bk : bv);
    unsigned short* ob = (chunk == 0) ? Qw : (chunk == 1 ? Kw : Vw);
    float4 bias4 = *(const float4*)(bb + jj);
    float4 acc[16];
    #pragma unroll
    for (int t = 0; t < 16; ++t) acc[t] = bias4;

    const float* wp = WqkvT + (chunk << 10) + jj;
    for (int k = 0; k < 256; ++k){
      const float4 w4 = *(const float4*)wp;  wp += 3072;
      const float4 xq0 = *(const float4*)&xs[k][0];
      const float4 xq1 = *(const float4*)&xs[k][4];
      const float4 xq2 = *(const float4*)&xs[k][8];
      const float4 xq3 = *(const float4*)&xs[k][12];
      const float xv[16] = {xq0.x,xq0.y,xq0.z,xq0.w, xq1.x,xq1.y,xq1.z,xq1.w,
                            xq2.x,xq2.y,xq2.z,xq2.w, xq3.x,xq3.y,xq3.z,xq3.w};
      #pragma unroll
      for (int t = 0; t < 16; ++t){
        acc[t].x = fmaf(xv[t], w4.x, acc[t].x);
        acc[t].y = fmaf(xv[t], w4.y, acc[t].y);
        acc[t].z = fmaf(xv[t], w4.z, acc[t].z);
        acc[t].w = fmaf(xv[t], w4.w, acc[t].w);
      }
    }
    #pragma unroll
    for (int t = 0; t < 16; ++t){
      const int n = n0 + t;
      const int b = n >> 9, s = n & 511;
      ushort4 pk;
      pk.x = f2bf(acc[t].x); pk.y = f2bf(acc[t].y);
      pk.z = f2bf(acc[t].z); pk.w = f2bf(acc[t].w);
      *(ushort4*)&ob[(((b << 2) + h) * 512 + s) * 256 + d] = pk;
    }
  }
}

// ---------------------------------------------------------------------------
// K2: spatial-temporal attention. block = (bh, 16 query rows), 256 thr.
// Q tile in registers (lane = si*4+kl holds k-slice kl*64..kl*64+63).
// scores in LDS stride-20 (b128-aligned, bank-safe). softmax over t=512.
// ---------------------------------------------------------------------------
__global__ __launch_bounds__(256) void k_attn(const unsigned short* __restrict__ Qw,
                                              const unsigned short* __restrict__ Kw,
                                              const unsigned short* __restrict__ Vw,
                                              unsigned short* __restrict__ Ow)
{
  __shared__ float sc[512 * 20];
  const int tid  = threadIdx.x;
  const int wid  = tid >> 6, lane = tid & 63;
  const int bh   = blockIdx.y;          // 0..127
  const int s0   = blockIdx.x << 4;     // 0..496
  const int si   = lane >> 2, kl = lane & 3;

  // ---- load Q fragment (same for every wave) ----
  float q[64];
  {
    const uint4* qp = (const uint4*)(Qw + (bh * 512 + s0 + si) * 256 + kl * 64);
    #pragma unroll
    for (int u = 0; u < 8; ++u){
      uint4 a = qp[u];
      q[u*8+0] = bf_lo(a.x); q[u*8+1] = bf_hi(a.x);
      q[u*8+2] = bf_lo(a.y); q[u*8+3] = bf_hi(a.y);
      q[u*8+4] = bf_lo(a.z); q[u*8+5] = bf_hi(a.z);
      q[u*8+6] = bf_lo(a.w); q[u*8+7] = bf_hi(a.w);
    }
  }

  // ---- scores: wave w covers t in [w*128, w*128+128) ----
  for (int i = 0; i < 128; ++i){
    const int t = (wid << 7) + i;
    const uint4* kp = (const uint4*)(Kw + (bh * 512 + t) * 256 + kl * 64);
    float acc = 0.f;
    #pragma unroll
    for (int u = 0; u < 8; ++u){
      uint4 a = kp[u];
      acc = fmaf(bf_lo(a.x), q[u*8+0], acc); acc = fmaf(bf_hi(a.x), q[u*8+1], acc);
      acc = fmaf(bf_lo(a.y), q[u*8+2], acc); acc = fmaf(bf_hi(a.y), q[u*8+3], acc);
      acc = fmaf(bf_lo(a.z), q[u*8+4], acc); acc = fmaf(bf_hi(a.z), q[u*8+5], acc);
      acc = fmaf(bf_lo(a.w), q[u*8+6], acc); acc = fmaf(bf_hi(a.w), q[u*8+7], acc);
    }
    acc += __shfl_xor(acc, 1);
    acc += __shfl_xor(acc, 2);
    if (kl == 0) sc[t * 20 + si] = acc * (1.0f / 256.0f);
  }
  __syncthreads();

  // ---- softmax over t (512) per si; 16 contiguous lanes per si ----
  {
    const int si2 = tid >> 4, tsub = tid & 15;
    float m = -1e30f;
    for (int j = 0; j < 32; ++j) m = fmaxf(m, sc[(tsub + 16*j) * 20 + si2]);
    #pragma unroll
    for (int mk = 1; mk <= 8; mk <<= 1) m = fmaxf(m, __shfl_xor(m, mk));
    float ssum = 0.f;
    for (int j = 0; j < 32; ++j){
      int a = (tsub + 16*j) * 20 + si2;
      float e = __expf(sc[a] - m);
      sc[a] = e; ssum += e;
    }
    #pragma unroll
    for (int mk = 1; mk <= 8; mk <<= 1) ssum += __shfl_xor(ssum, mk);
    float inv = 1.0f / ssum;
    for (int j = 0; j < 32; ++j) sc[(tsub + 16*j) * 20 + si2] *= inv;
  }
  __syncthreads();

  // ---- output: wave w owns si0=w*4..+3; lane owns d = lane*4..+3 ----
  const int si0 = wid << 2;
  const int d0  = lane << 2;
  float4 a0 = {0,0,0,0}, a1 = {0,0,0,0}, a2 = {0,0,0,0}, a3 = {0,0,0,0};
  for (int t = 0; t < 512; ++t){
    const float4 p = *(const float4*)&sc[t * 20 + si0];
    uint2 vv = *(const uint2*)(Vw + (bh * 512 + t) * 256 + d0);
    float v0 = bf_lo(vv.x), v1 = bf_hi(vv.x), v2 = bf_lo(vv.y), v3 = bf_hi(vv.y);
    a0.x = fmaf(p.x, v0, a0.x); a0.y = fmaf(p.x, v1, a0.y); a0.z = fmaf(p.x, v2, a0.z); a0.w = fmaf(p.x, v3, a0.w);
    a1.x = fmaf(p.y, v0, a1.x); a1.y = fmaf(p.y, v1, a1.y); a1.z = fmaf(p.y, v2, a1.z); a1.w = fmaf(p.y, v3, a1.w);
    a2.x = fmaf(p.z, v0, a2.x); a2.y = fmaf(p.z, v1, a2.y); a2.z = fmaf(p.z, v2, a2.z); a2.w = fmaf(p.z, v3, a2.w);
    a3.x = fmaf(p.w, v0, a3.x); a3.y = fmaf(p.w, v1, a3.y); a3.z = fmaf(p.w, v2, a3.z); a3.w = fmaf(p.w, v3, a3.w);
  }
  const int b = bh >> 2, h = bh & 3;
  #pragma unroll
  for (int r = 0; r < 4; ++r){
    const float4 ac = (r == 0) ? a0 : (r == 1 ? a1 : (r == 2 ? a2 : a3));
    const int n = b * 512 + s0 + si0 + r;
    ushort4 pk;
    pk.x = f2bf(ac.x); pk.y = f2bf(ac.y); pk.z = f2bf(ac.z); pk.w = f2bf(ac.w);
    *(ushort4*)&Ow[n * 1024 + h * 256 + d0] = pk;
  }
}

// ---------------------------------------------------------------------------
// K3: x1 = LN(o @ Wlin1^T + blin1 + x).  wave-per-token, k across lanes,
// butterfly reduce; 8 waves/block share Wlin1 rows via L1.
// ---------------------------------------------------------------------------
__global__ __launch_bounds__(512) void k_lin1(const unsigned short* __restrict__ Ow,
                                              const float* __restrict__ Wlin1,
                                              const float* __restrict__ blin1,
                                              const float* __restrict__ x,
                                              float* __restrict__ x1)
{
  const int lane = threadIdx.x & 63;
  const int n    = blockIdx.x * 8 + (threadIdx.x >> 6);

  float of[16];
  {
    const uint4* op = (const uint4*)(Ow + n * 1024 + lane * 16);
    uint4 a = op[0], b = op[1];
    of[0]=bf_lo(a.x); of[1]=bf_hi(a.x); of[2]=bf_lo(a.y); of[3]=bf_hi(a.y);
    of[4]=bf_lo(a.z); of[5]=bf_hi(a.z); of[6]=bf_lo(a.w); of[7]=bf_hi(a.w);
    of[8]=bf_lo(b.x); of[9]=bf_hi(b.x); of[10]=bf_lo(b.y); of[11]=bf_hi(b.y);
    of[12]=bf_lo(b.z); of[13]=bf_hi(b.z); of[14]=bf_lo(b.w); of[15]=bf_hi(b.w);
  }

  float outl[4];
  #pragma unroll
  for (int seg = 0; seg < 4; ++seg){
    float keep = 0.f;
    #pragma unroll 4
    for (int dd = 0; dd < 64; ++dd){
      const float* wr = Wlin1 + (seg * 64 + dd) * 1024 + lane * 16;
      const float4 w0 = *(const float4*)(wr);
      const float4 w1 = *(const float4*)(wr + 4);
      const float4 w2 = *(const float4*)(wr + 8);
      const float4 w3 = *(const float4*)(wr + 12);
      float acc;
      acc = of[0]*w0.x;              acc = fmaf(of[1], w0.y, acc);
      acc = fmaf(of[2], w0.z, acc);  acc = fmaf(of[3], w0.w, acc);
      acc = fmaf(of[4], w1.x, acc);  acc = fmaf(of[5], w1.y, acc);
      acc = fmaf(of[6], w1.z, acc);  acc = fmaf(of[7], w1.w, acc);
      acc = fmaf(of[8], w2.x, acc);  acc = fmaf(of[9], w2.y, acc);
      acc = fmaf(of[10], w2.z, acc); acc = fmaf(of[11], w2.w, acc);
      acc = fmaf(of[12], w3.x, acc); acc = fmaf(of[13], w3.y, acc);
      acc = fmaf(of[14], w3.z, acc); acc = fmaf(of[15], w3.w, acc);
      acc += __shfl_xor(acc, 32); acc += __shfl_xor(acc, 16); acc += __shfl_xor(acc, 8);
      acc += __shfl_xor(acc, 4);  acc += __shfl_xor(acc, 2);  acc += __shfl_xor(acc, 1);
      keep = (lane == dd) ? acc : keep;
    }
    outl[seg] = keep;
  }

  // bias + residual + LN (mean/std, ddof=1, no eps)
  float v0 = outl[0] + blin1[lane]       + x[n*256 + lane];
  float v1 = outl[1] + blin1[64 + lane]  + x[n*256 + 64 + lane];
  float v2 = outl[2] + blin1[128 + lane] + x[n*256 + 128 + lane];
  float v3 = outl[3] + blin1[192 + lane] + x[n*256 + 192 + lane];
  float sum = v0 + v1 + v2 + v3;
  #pragma unroll
  for (int mk = 32; mk >= 1; mk >>= 1) sum += __shfl_xor(sum, mk);
  float mean = sum * (1.0f / 256.0f);
  float e0 = v0 - mean, e1 = v1 - mean, e2 = v2 - mean, e3 = v3 - mean;
  float sq = e0*e0 + e1*e1 + e2*e2 + e3*e3;
  #pragma unroll
  for (int mk = 32; mk >= 1; mk >>= 1) sq += __shfl_xor(sq, mk);
  float inv = rsqrtf(sq * (1.0f / 255.0f));
  x1[n*256 + lane]       = e0 * inv;
  x1[n*256 + 64 + lane]  = e1 * inv;
  x1[n*256 + 128 + lane] = e2 * inv;
  x1[n*256 + 192 + lane] = e3 * inv;
}

// ---------------------------------------------------------------------------
// K4: CNN patch attention per token (block = 1 token, 256 thr, all LDS).
// y[n][p*16+jj] = (oc2 @ Wlo^T + blo), pre-Wlout.
// ---------------------------------------------------------------------------
__global__ __launch_bounds__(256) void k_patch(const float* __restrict__ x1,
    const float* __restrict__ Wqc, const float* __restrict__ bqc,
    const float* __restrict__ Wkc, const float* __restrict__ bkc,
    const float* __restrict__ Wvl, const float* __restrict__ bvl,
    const float* __restrict__ Wlo, const float* __restrict__ blo,
    float* __restrict__ y)
{
  __shared__ float xp[16][17];
  __shared__ float qkv[3][16][132];     // Qc,Kc,Vc : [p][c], bank-safe stride
  __shared__ float am[4][16][17];       // [h][p][q]
  __shared__ float oc2[16][132];        // [p][h*32+c]
  const int tid = threadIdx.x;
  const int n   = blockIdx.x;

  xp[tid >> 4][tid & 15] = x1[n * 256 + tid];
  __syncthreads();

  // QKVc: conv1d(kernel=stride=16) == per-patch linear
  #pragma unroll
  for (int r = 0; r < 24; ++r){
    const int m = r >> 3;
    const int p = ((r & 7) << 1) + (tid >> 7);
    const int c = tid & 127;
    const float* W  = (m == 0) ? Wqc : (m == 1 ? Wkc : Wvl);
    const float* bb = (m == 0) ? bqc : (m == 1 ? bkc : bvl);
    const float4* wr = (const float4*)(W + c * 16);
    const float4 w0 = wr[0], w1 = wr[1], w2 = wr[2], w3 = wr[3];
    float acc = bb[c];
    acc = fmaf(xp[p][0],  w0.x, acc); acc = fmaf(xp[p][1],  w0.y, acc);
    acc = fmaf(xp[p][2],  w0.z, acc); acc = fmaf(xp[p][3],  w0.w, acc);
    acc = fmaf(xp[p][4],  w1.x, acc); acc = fmaf(xp[p][5],  w1.y, acc);
    acc = fmaf(xp[p][6],  w1.z, acc); acc = fmaf(xp[p][7],  w1.w, acc);
    acc = fmaf(xp[p][8],  w2.x, acc); acc = fmaf(xp[p][9],  w2.y, acc);
    acc = fmaf(xp[p][10], w2.z, acc); acc = fmaf(xp[p][11], w2.w, acc);
    acc = fmaf(xp[p][12], w3.x, acc); acc = fmaf(xp[p][13], w3.y, acc);
    acc = fmaf(xp[p][14], w3.z, acc); acc = fmaf(xp[p][15], w3.w, acc);
    qkv[m][p][c] = acc;
  }
  __syncthreads();

  // scores per head h=r: am[h][p][q] = Qc[p]·Kc[q] (32-dim) / 16
  #pragma unroll
  for (int r = 0; r < 4; ++r){
    const int p = tid >> 4, qi = tid & 15;
    const float4* qa = (const float4*)&qkv[0][p][r * 32];
    const float4* ka = (const float4*)&qkv[1][qi][r * 32];
    float acc = 0.f;
    #pragma unroll
    for (int cc = 0; cc < 8; ++cc){
      float4 qv = qa[cc], kv = ka[cc];
      acc = fmaf(qv.x, kv.x, acc); acc = fmaf(qv.y, kv.y, acc);
      acc = fmaf(qv.z, kv.z, acc); acc = fmaf(qv.w, kv.w, acc);
    }
    am[r][p][qi] = acc * (1.0f / 16.0f);
  }
  __syncthreads();

  // softmax over q, 64 rows (h,p)
  if (tid < 64){
    const int h = tid >> 4, p = tid & 15;
    float m = -1e30f;
    #pragma unroll
    for (int qi = 0; qi < 16; ++qi) m = fmaxf(m, am[h][p][qi]);
    float s = 0.f;
    #pragma unroll
    for (int qi = 0; qi < 16; ++qi){
      float e = __expf(am[h][p][qi] - m);
      am[h][p][qi] = e; s += e;
    }
    float inv = 1.0f / s;
    #pragma unroll
    for (int qi = 0; qi < 16; ++qi) am[h][p][qi] *= inv;
  }
  __syncthreads();

  // oc2[p][h*32+c] = sum_q am[h][p][q] * Vc[q][h*32+c]
  #pragma unroll
  for (int r = 0; r < 8; ++r){
    const int h = r >> 1;
    const int p = ((r & 1) << 3) + (tid >> 5);
    const int c = tid & 31;
    float acc = 0.f;
    #pragma unroll
    for (int qi = 0; qi < 16; ++qi)
      acc = fmaf(am[h][p][qi], qkv[2][qi][h * 32 + c], acc);
    oc2[p][h * 32 + c] = acc;
  }
  __syncthreads();

  // Wlo: y[p][jj] = oc2[p]·Wlo[jj] + blo[jj]
  {
    const int p = tid >> 4, jj = tid & 15;
    const float4* wr = (const float4*)(Wlo + jj * 128);
    const float4* ov = (const float4*)&oc2[p][0];
    float acc = blo[jj];
    #pragma unroll
    for (int u = 0; u < 32; ++u){
      float4 w = wr[u], o4 = ov[u];
      acc = fmaf(o4.x, w.x, acc); acc = fmaf(o4.y, w.y, acc);
      acc = fmaf(o4.z, w.z, acc); acc = fmaf(o4.w, w.w, acc);
    }
    y[n * 256 + tid] = acc;
  }
}

// ---------------------------------------------------------------------------
// K5: out = LN(y @ Wlout^T + blout + x1). wave-per-token butterfly GEMV.
// ---------------------------------------------------------------------------
__global__ __launch_bounds__(512) void k_out(const float* __restrict__ y,
                                             const float* __restrict__ Wlout,
                                             const float* __restrict__ blout,
                                             const float* __restrict__ x1,
                                             float* __restrict__ out)
{
  const int lane = threadIdx.x & 63;
  const int n    = blockIdx.x * 8 + (threadIdx.x >> 6);
  const float4 yf = *(const float4*)(y + n * 256 + lane * 4);

  float outl[4];
  #pragma unroll
  for (int seg = 0; seg < 4; ++seg){
    float keep = 0.f;
    #pragma unroll 4
    for (int dd = 0; dd < 64; ++dd){
      const float4 w = *(const float4*)(Wlout + (seg * 64 + dd) * 256 + lane * 4);
      float acc;
      acc = yf.x * w.x; acc = fmaf(yf.y, w.y, acc);
      acc = fmaf(yf.z, w.z, acc); acc = fmaf(yf.w, w.w, acc);
      acc += __shfl_xor(acc, 32); acc += __shfl_xor(acc, 16); acc += __shfl_xor(acc, 8);
      acc += __shfl_xor(acc, 4);  acc += __shfl_xor(acc, 2);  acc += __shfl_xor(acc, 1);
      keep = (lane == dd) ? acc : keep;
    }
    outl[seg] = keep;
  }

  float v0 = outl[0] + blout[lane]       + x1[n*256 + lane];
  float v1 = outl[1] + blout[64 + lane]  + x1[n*256 + 64 + lane];
  float v2 = outl[2] + blout[128 + lane] + x1[n*256 + 128 + lane];
  float v3 = outl[3] + blout[192 + lane] + x1[n*256 + 192 + lane];
  float sum = v0 + v1 + v2 + v3;
  #pragma unroll
  for (int mk = 32; mk >= 1; mk >>= 1) sum += __shfl_xor(sum, mk);
  float mean = sum * (1.0f / 256.0f);
  float e0 = v0 - mean, e1 = v1 - mean, e2 = v2 - mean, e3 = v3 - mean;
  float sq = e0*e0 + e1*e1 + e2*e2 + e3*e3;
  #pragma unroll
  for (int mk = 32; mk >= 1; mk >>= 1) sq += __shfl_xor(sq, mk);
  float inv = rsqrtf(sq * (1.0f / 255.0f));
  out[n*256 + lane]       = e0 * inv;
  out[n*256 + 64 + lane]  = e1 * inv;
  out[n*256 + 128 + lane] = e2 * inv;
  out[n*256 + 192 + lane] = e3 * inv;
}

// ---------------------------------------------------------------------------
extern "C" void kernel_launch(void* const* d_in, const int* in_sizes, int n_in,
                              void* d_out, int out_size, void* d_ws, size_t ws_size,
                              hipStream_t stream)
{
  const float* x     = (const float*)d_in[0];
  const float* Wq    = (const float*)d_in[1];
  const float* bq    = (const float*)d_in[2];
  const float* Wk    = (const float*)d_in[3];
  const float* bk    = (const float*)d_in[4];
  const float* Wv    = (const float*)d_in[5];
  const float* bv    = (const float*)d_in[6];
  const float* Wlin1 = (const float*)d_in[7];
  const float* blin1 = (const float*)d_in[8];
  const float* Wqc   = (const float*)d_in[9];
  const float* bqc   = (const float*)d_in[10];
  const float* Wkc   = (const float*)d_in[11];
  const float* bkc   = (const float*)d_in[12];
  const float* Wvl   = (const float*)d_in[13];
  const float* bvl   = (const float*)d_in[14];
  const float* Wlo   = (const float*)d_in[15];
  const float* blo   = (const float*)d_in[16];
  const float* Wlout = (const float*)d_in[17];
  const float* blout = (const float*)d_in[18];
  float* out = (float*)d_out;

  // workspace layout (bytes):
  // 0         Q  bf16 [128][512][256]  (33.55 MB)
  // 33554432  K  bf16                  (33.55 MB)
  // 67108864  V  bf16                  (33.55 MB)
  // 100663296 o  bf16 [16384][1024]    (33.55 MB)
  // 134217728 x1 f32  [16384][256]     (16.78 MB)
  // 150994944 y  f32  [16384][256]     (16.78 MB)
  // 167772160 WqkvT f32 [256][3072]    ( 3.15 MB)   total ~171 MB
  char* w = (char*)d_ws;
  unsigned short* Qw = (unsigned short*)w;
  unsigned short* Kw = Qw + 16777216;
  unsigned short* Vw = Kw + 16777216;
  unsigned short* Ow = Vw + 16777216;
  float* x1    = (float*)(w + 134217728);
  float* y     = x1 + 4194304;
  float* WqkvT = y + 4194304;

  k_prep <<<3072, 256, 0, stream>>>(Wq, Wk, Wv, WqkvT);
  k_qkv  <<<1024, 256, 0, stream>>>(x, WqkvT, bq, bk, bv, Qw, Kw, Vw);
  k_attn <<<dim3(32, 128), 256, 0, stream>>>(Qw, Kw, Vw, Ow);
  k_lin1 <<<2048, 512, 0, stream>>>(Ow, Wlin1, blin1, x, x1);
  k_patch<<<16384, 256, 0, stream>>>(x1, Wqc, bqc, Wkc, bkc, Wvl, bvl, Wlo, blo, y);
  k_out  <<<2048, 512, 0, stream>>>(y, Wlout, blout, x1, out);
}

// Round 2
// 2795.133 us; speedup vs baseline: 1.6925x; 1.6925x over previous
//
#include <hip/hip_runtime.h>
#include <hip/hip_bf16.h>
#include <math.h>

// ---- problem constants ----
// bs=32, S=512, D=256, HS=4 heads (head dim = D = 256!), NT = 16384 tokens
// patch: NP=16 patches x P=16, CC=128, HP=4 heads x CE=32

typedef __attribute__((ext_vector_type(8))) short bf16x8;
typedef __attribute__((ext_vector_type(4))) float f32x4;

__device__ __forceinline__ float bf_lo(unsigned u){ return __uint_as_float(u << 16); }
__device__ __forceinline__ float bf_hi(unsigned u){ return __uint_as_float(u & 0xFFFF0000u); }
__device__ __forceinline__ unsigned short f2bf(float f){
  unsigned u = __float_as_uint(f);
  return (unsigned short)((u + 0x7FFFu + ((u >> 16) & 1u)) >> 16);   // RNE
}
__device__ __forceinline__ unsigned pack2bf(float a, float b){
  return (unsigned)f2bf(a) | ((unsigned)f2bf(b) << 16);
}
// async 16B global->LDS (dest = wave-uniform base + lane*16)
__device__ __forceinline__ void gld16(const void* g, void* l){
  __builtin_amdgcn_global_load_lds((const __attribute__((address_space(1))) void*)g,
                                   (__attribute__((address_space(3))) void*)l, 16, 0, 0);
}

// ---------------------------------------------------------------------------
// prep: WqkvT[k][j] (k<256, j<3072) = concat(Wq,Wk,Wv)[j][k]
// ---------------------------------------------------------------------------
__global__ __launch_bounds__(256) void k_prep(const float* __restrict__ Wq,
                                              const float* __restrict__ Wk,
                                              const float* __restrict__ Wv,
                                              float* __restrict__ WqkvT)
{
  int idx = blockIdx.x * 256 + threadIdx.x;       // 786432 total
  int k = idx / 3072, j = idx - k * 3072;
  const float* W = (j < 1024) ? Wq : (j < 2048 ? Wk : Wv);
  int jj = j & 1023;
  WqkvT[idx] = W[jj * 256 + k];
}

// ---------------------------------------------------------------------------
// K1: QKV projection. block = 16 tokens, 256 threads; thread owns 4 output
// cols; writes bf16 Q/K/V in [bh][s][d] layout.
// ---------------------------------------------------------------------------
__global__ __launch_bounds__(256) void k_qkv(const float* __restrict__ x,
                                             const float* __restrict__ WqkvT,
                                             const float* __restrict__ bq,
                                             const float* __restrict__ bk,
                                             const float* __restrict__ bv,
                                             unsigned short* __restrict__ Qw,
                                             unsigned short* __restrict__ Kw,
                                             unsigned short* __restrict__ Vw)
{
  __shared__ float xs[256][16];          // [k][t]
  const int tid = threadIdx.x;
  const int n0  = blockIdx.x << 4;
  for (int i = tid; i < 4096; i += 256){
    int t = i >> 8, k = i & 255;
    xs[k][t] = x[(n0 + t) * 256 + k];
  }
  __syncthreads();

  const int h  = tid >> 6;               // head of this thread's 4 cols
  const int d  = (tid << 2) & 255;
  const int jj = tid << 2;               // col within the 1024-wide matrix

  #pragma unroll 1
  for (int chunk = 0; chunk < 3; ++chunk){
    const float* bb = (chunk == 0) ? bq : (chunk == 1 ? bk : bv);
    unsigned short* ob = (chunk == 0) ? Qw : (chunk == 1 ? Kw : Vw);
    float4 bias4 = *(const float4*)(bb + jj);
    float4 acc[16];
    #pragma unroll
    for (int t = 0; t < 16; ++t) acc[t] = bias4;

    const float* wp = WqkvT + (chunk << 10) + jj;
    for (int k = 0; k < 256; ++k){
      const float4 w4 = *(const float4*)wp;  wp += 3072;
      const float4 xq0 = *(const float4*)&xs[k][0];
      const float4 xq1 = *(const float4*)&xs[k][4];
      const float4 xq2 = *(const float4*)&xs[k][8];
      const float4 xq3 = *(const float4*)&xs[k][12];
      const float xv[16] = {xq0.x,xq0.y,xq0.z,xq0.w, xq1.x,xq1.y,xq1.z,xq1.w,
                            xq2.x,xq2.y,xq2.z,xq2.w, xq3.x,xq3.y,xq3.z,xq3.w};
      #pragma unroll
      for (int t = 0; t < 16; ++t){
        acc[t].x = fmaf(xv[t], w4.x, acc[t].x);
        acc[t].y = fmaf(xv[t], w4.y, acc[t].y);
        acc[t].z = fmaf(xv[t], w4.z, acc[t].z);
        acc[t].w = fmaf(xv[t], w4.w, acc[t].w);
      }
    }
    #pragma unroll
    for (int t = 0; t < 16; ++t){
      const int n = n0 + t;
      const int b = n >> 9, s = n & 511;
      ushort4 pk;
      pk.x = f2bf(acc[t].x); pk.y = f2bf(acc[t].y);
      pk.z = f2bf(acc[t].z); pk.w = f2bf(acc[t].w);
      *(ushort4*)&ob[(((b << 2) + h) * 512 + s) * 256 + d] = pk;
    }
  }
}

// ---------------------------------------------------------------------------
// K1b: V transpose per bh: Vt[bh][d][s] from Vw[bh][s][d], 64x64 tiles.
// ---------------------------------------------------------------------------
__global__ __launch_bounds__(256) void k_vt(const unsigned short* __restrict__ Vw,
                                            unsigned short* __restrict__ Vt)
{
  __shared__ unsigned short tile[64][72];
  const int tid = threadIdx.x;
  const int s0 = blockIdx.x << 6, d0 = blockIdx.y << 6, bh = blockIdx.z;
  const unsigned short* src = Vw + (bh * 512 + s0) * 256 + d0;
  #pragma unroll
  for (int p = 0; p < 2; ++p){
    int idx = p * 256 + tid;
    int sl = idx >> 3, db = (idx & 7) * 8;
    *(uint4*)&tile[sl][db] = *(const uint4*)(src + sl * 256 + db);
  }
  __syncthreads();
  #pragma unroll
  for (int p = 0; p < 2; ++p){
    int idx = p * 256 + tid;
    int dl = idx >> 3, sb = (idx & 7) * 8, m = idx & 7;
    unsigned short r[8] __attribute__((aligned(16)));
    #pragma unroll
    for (int k = 0; k < 8; ++k){
      int kk = (k + m) & 7;                 // stagger: bank-conflict-free
      r[kk] = tile[sb + kk][dl];
    }
    *(uint4*)(Vt + (bh * 256 + d0 + dl) * 512 + s0 + sb) = *(uint4*)r;
  }
}

// ---------------------------------------------------------------------------
// K2: MFMA flash attention. 8 waves x 16 q-rows = 128 q/block, grid (4,128).
// Swapped QK^T: S^T = K.Q^T so softmax state is per-lane scalar (si=lane&15).
// O^T = Vt.P^T. K/Vt staged dbuf via global_load_lds w/ pre-swizzled source.
// Dynamic LDS: K 2x32K @0/65536, V 2x32K @32768/98304, P 8x2K @131072.
// ---------------------------------------------------------------------------
__global__ __launch_bounds__(512) void k_attn(const unsigned short* __restrict__ Qw,
                                              const unsigned short* __restrict__ Kw,
                                              const unsigned short* __restrict__ Vt,
                                              unsigned short* __restrict__ Ow)
{
  extern __shared__ char smem[];
  const int tid  = threadIdx.x;
  const int wid  = tid >> 6, lane = tid & 63;
  const int g    = lane >> 4, li = lane & 15, l7 = lane & 7;
  const int bh   = blockIdx.y;
  const int sblk = blockIdx.x << 7;
  const int q0   = sblk + (wid << 4);

  char* const PB = smem + 131072 + (wid << 11);

  // ---- stage helpers (LDS dest linear; source pre-swizzled by row&7) ----
  auto stageK = [&](char* kbuf, int t0){
    const unsigned short* base = Kw + ((bh << 9) + t0 + (wid << 3)) * 256;
    char* dst = kbuf + (wid << 12);
    #pragma unroll
    for (int c = 0; c < 4; ++c){
      int r  = (c << 1) + (lane >> 5);
      int cs = ((((lane & 31) << 4) ^ (r << 4)) >> 1);
      gld16(base + (r << 8) + cs, dst + (c << 10));
    }
  };
  auto stageV = [&](char* vbuf, int t0){
    const unsigned short* base = Vt + (bh * 256 + wid * 32) * 512 + t0;
    char* dst = vbuf + (wid << 12);
    int cs = ((lane & 7) ^ (lane >> 3)) << 3;
    #pragma unroll
    for (int c = 0; c < 4; ++c){
      int r = (c << 3) + (lane >> 3);
      gld16(base + (r << 9) + cs, dst + (c << 10));
    }
  };

  stageK(smem, 0);
  stageV(smem + 32768, 0);

  // ---- Q B-frags: lane holds Q[q0+li][kk*32 + g*8 .. +7] ----
  bf16x8 qf[8];
  {
    const unsigned short* qp = Qw + ((bh << 9) + q0 + li) * 256 + (g << 3);
    #pragma unroll
    for (int kk = 0; kk < 8; ++kk)
      qf[kk] = *(const bf16x8*)(qp + (kk << 5));
  }

  f32x4 o[16];
  #pragma unroll
  for (int df = 0; df < 16; ++df) o[df] = (f32x4){0.f,0.f,0.f,0.f};
  float mrun = -3.0e38f, lrun = 0.f;

  __syncthreads();
  const float inv256 = 1.0f / 256.0f;

  for (int t = 0; t < 8; ++t){
    char* kb = (t & 1) ? (smem + 65536) : smem;
    char* vb = (t & 1) ? (smem + 98304) : (smem + 32768);
    if (t < 7){
      char* kn = (t & 1) ? smem : (smem + 65536);
      char* vn = (t & 1) ? (smem + 32768) : (smem + 98304);
      stageK(kn, (t + 1) << 6);
      stageV(vn, (t + 1) << 6);
    }

    // ---- S^T(64t x 16si) = K . Q^T ----
    f32x4 st[4];
    #pragma unroll
    for (int tf = 0; tf < 4; ++tf){
      st[tf] = (f32x4){0.f,0.f,0.f,0.f};
      const int rowb = ((tf << 4) + li) << 9;
      #pragma unroll
      for (int kk = 0; kk < 8; ++kk){
        const int colb = ((kk << 6) + (g << 4)) ^ (l7 << 4);
        bf16x8 kf = *(const bf16x8*)(kb + rowb + colb);
        st[tf] = __builtin_amdgcn_mfma_f32_16x16x32_bf16(kf, qf[kk], st[tf], 0, 0, 0);
      }
    }

    // ---- online softmax; state per-lane (si = li) ----
    float s[16];
    #pragma unroll
    for (int tf = 0; tf < 4; ++tf){
      s[tf*4+0] = st[tf].x * inv256; s[tf*4+1] = st[tf].y * inv256;
      s[tf*4+2] = st[tf].z * inv256; s[tf*4+3] = st[tf].w * inv256;
    }
    float pmax = s[0];
    #pragma unroll
    for (int i = 1; i < 16; ++i) pmax = fmaxf(pmax, s[i]);
    pmax = fmaxf(pmax, __shfl_xor(pmax, 16));
    pmax = fmaxf(pmax, __shfl_xor(pmax, 32));
    float mnew = fmaxf(mrun, pmax);
    float corr = __expf(mrun - mnew);
    float psum = 0.f;
    #pragma unroll
    for (int i = 0; i < 16; ++i){ s[i] = __expf(s[i] - mnew); psum += s[i]; }
    psum += __shfl_xor(psum, 16);
    psum += __shfl_xor(psum, 32);
    lrun = lrun * corr + psum;
    if (!__all(mnew == mrun)){
      #pragma unroll
      for (int df = 0; df < 16; ++df) o[df] *= corr;
    }
    mrun = mnew;

    // ---- P -> P_lds[si][t] bf16 (swizzled), per-wave private ----
    #pragma unroll
    for (int tf = 0; tf < 4; ++tf){
      uint2 pk; pk.x = pack2bf(s[tf*4+0], s[tf*4+1]); pk.y = pack2bf(s[tf*4+2], s[tf*4+3]);
      const int addr = (li << 7) + (((tf << 5) + (g << 3)) ^ (l7 << 4));
      *(uint2*)(PB + addr) = pk;
    }
    __asm__ volatile("s_waitcnt lgkmcnt(0)" ::: "memory");
    __builtin_amdgcn_sched_barrier(0);

    // ---- O^T(256d x 16si) += Vt_tile . P^T ----
    #pragma unroll
    for (int tt = 0; tt < 2; ++tt){
      const int colb = ((tt << 6) + (g << 4)) ^ (l7 << 4);
      bf16x8 pb = *(const bf16x8*)(PB + (li << 7) + colb);
      #pragma unroll
      for (int df = 0; df < 16; ++df){
        bf16x8 va = *(const bf16x8*)(vb + (((df << 4) + li) << 7) + colb);
        o[df] = __builtin_amdgcn_mfma_f32_16x16x32_bf16(va, pb, o[df], 0, 0, 0);
      }
    }
    __syncthreads();
  }

  // ---- epilogue: O /= l, transpose via LDS, coalesced bf16 store ----
  float inv = 1.0f / lrun;
  #pragma unroll
  for (int df = 0; df < 16; ++df) o[df] *= inv;

  char* const OT = smem + (wid << 14);    // 8KB per wave inside staging area
  #pragma unroll
  for (int df = 0; df < 16; ++df){
    uint2 pk; pk.x = pack2bf(o[df].x, o[df].y); pk.y = pack2bf(o[df].z, o[df].w);
    const int addr = (li << 9) + (((df << 5) + (g << 3)) ^ (l7 << 4));
    *(uint2*)(OT + addr) = pk;
  }
  __asm__ volatile("s_waitcnt lgkmcnt(0)" ::: "memory");
  __builtin_amdgcn_sched_barrier(0);
  const int b = bh >> 2, h = bh & 3;
  #pragma unroll
  for (int p = 0; p < 8; ++p){
    const int row  = (p << 1) + (lane >> 5);
    const int colb = ((lane & 31) << 4) ^ ((row & 7) << 4);
    uint4 vv = *(const uint4*)(OT + (row << 9) + colb);
    const int d0 = (lane & 31) << 3;
    *(uint4*)(Ow + ((b << 9) + sblk + (wid << 4) + row) * 1024 + (h << 8) + d0) = vv;
  }
}

// ---------------------------------------------------------------------------
// K3: x1 = LN(o @ Wlin1^T + blin1 + x).  wave-per-token butterfly GEMV.
// ---------------------------------------------------------------------------
__global__ __launch_bounds__(512) void k_lin1(const unsigned short* __restrict__ Ow,
                                              const float* __restrict__ Wlin1,
                                              const float* __restrict__ blin1,
                                              const float* __restrict__ x,
                                              float* __restrict__ x1)
{
  const int lane = threadIdx.x & 63;
  const int n    = blockIdx.x * 8 + (threadIdx.x >> 6);

  float of[16];
  {
    const uint4* op = (const uint4*)(Ow + n * 1024 + lane * 16);
    uint4 a = op[0], b = op[1];
    of[0]=bf_lo(a.x); of[1]=bf_hi(a.x); of[2]=bf_lo(a.y); of[3]=bf_hi(a.y);
    of[4]=bf_lo(a.z); of[5]=bf_hi(a.z); of[6]=bf_lo(a.w); of[7]=bf_hi(a.w);
    of[8]=bf_lo(b.x); of[9]=bf_hi(b.x); of[10]=bf_lo(b.y); of[11]=bf_hi(b.y);
    of[12]=bf_lo(b.z); of[13]=bf_hi(b.z); of[14]=bf_lo(b.w); of[15]=bf_hi(b.w);
  }

  float outl[4];
  #pragma unroll
  for (int seg = 0; seg < 4; ++seg){
    float keep = 0.f;
    #pragma unroll 4
    for (int dd = 0; dd < 64; ++dd){
      const float* wr = Wlin1 + (seg * 64 + dd) * 1024 + lane * 16;
      const float4 w0 = *(const float4*)(wr);
      const float4 w1 = *(const float4*)(wr + 4);
      const float4 w2 = *(const float4*)(wr + 8);
      const float4 w3 = *(const float4*)(wr + 12);
      float acc;
      acc = of[0]*w0.x;              acc = fmaf(of[1], w0.y, acc);
      acc = fmaf(of[2], w0.z, acc);  acc = fmaf(of[3], w0.w, acc);
      acc = fmaf(of[4], w1.x, acc);  acc = fmaf(of[5], w1.y, acc);
      acc = fmaf(of[6], w1.z, acc);  acc = fmaf(of[7], w1.w, acc);
      acc = fmaf(of[8], w2.x, acc);  acc = fmaf(of[9], w2.y, acc);
      acc = fmaf(of[10], w2.z, acc); acc = fmaf(of[11], w2.w, acc);
      acc = fmaf(of[12], w3.x, acc); acc = fmaf(of[13], w3.y, acc);
      acc = fmaf(of[14], w3.z, acc); acc = fmaf(of[15], w3.w, acc);
      acc += __shfl_xor(acc, 32); acc += __shfl_xor(acc, 16); acc += __shfl_xor(acc, 8);
      acc += __shfl_xor(acc, 4);  acc += __shfl_xor(acc, 2);  acc += __shfl_xor(acc, 1);
      keep = (lane == dd) ? acc : keep;
    }
    outl[seg] = keep;
  }

  float v0 = outl[0] + blin1[lane]       + x[n*256 + lane];
  float v1 = outl[1] + blin1[64 + lane]  + x[n*256 + 64 + lane];
  float v2 = outl[2] + blin1[128 + lane] + x[n*256 + 128 + lane];
  float v3 = outl[3] + blin1[192 + lane] + x[n*256 + 192 + lane];
  float sum = v0 + v1 + v2 + v3;
  #pragma unroll
  for (int mk = 32; mk >= 1; mk >>= 1) sum += __shfl_xor(sum, mk);
  float mean = sum * (1.0f / 256.0f);
  float e0 = v0 - mean, e1 = v1 - mean, e2 = v2 - mean, e3 = v3 - mean;
  float sq = e0*e0 + e1*e1 + e2*e2 + e3*e3;
  #pragma unroll
  for (int mk = 32; mk >= 1; mk >>= 1) sq += __shfl_xor(sq, mk);
  float inv = rsqrtf(sq * (1.0f / 255.0f));
  x1[n*256 + lane]       = e0 * inv;
  x1[n*256 + 64 + lane]  = e1 * inv;
  x1[n*256 + 128 + lane] = e2 * inv;
  x1[n*256 + 192 + lane] = e3 * inv;
}

// ---------------------------------------------------------------------------
// K4: CNN patch attention per token (block = 1 token, 256 thr, all LDS).
// ---------------------------------------------------------------------------
__global__ __launch_bounds__(256) void k_patch(const float* __restrict__ x1,
    const float* __restrict__ Wqc, const float* __restrict__ bqc,
    const float* __restrict__ Wkc, const float* __restrict__ bkc,
    const float* __restrict__ Wvl, const float* __restrict__ bvl,
    const float* __restrict__ Wlo, const float* __restrict__ blo,
    float* __restrict__ y)
{
  __shared__ float xp[16][17];
  __shared__ float qkv[3][16][132];
  __shared__ float am[4][16][17];
  __shared__ float oc2[16][132];
  const int tid = threadIdx.x;
  const int n   = blockIdx.x;

  xp[tid >> 4][tid & 15] = x1[n * 256 + tid];
  __syncthreads();

  #pragma unroll
  for (int r = 0; r < 24; ++r){
    const int m = r >> 3;
    const int p = ((r & 7) << 1) + (tid >> 7);
    const int c = tid & 127;
    const float* W  = (m == 0) ? Wqc : (m == 1 ? Wkc : Wvl);
    const float* bb = (m == 0) ? bqc : (m == 1 ? bkc : bvl);
    const float4* wr = (const float4*)(W + c * 16);
    const float4 w0 = wr[0], w1 = wr[1], w2 = wr[2], w3 = wr[3];
    float acc = bb[c];
    acc = fmaf(xp[p][0],  w0.x, acc); acc = fmaf(xp[p][1],  w0.y, acc);
    acc = fmaf(xp[p][2],  w0.z, acc); acc = fmaf(xp[p][3],  w0.w, acc);
    acc = fmaf(xp[p][4],  w1.x, acc); acc = fmaf(xp[p][5],  w1.y, acc);
    acc = fmaf(xp[p][6],  w1.z, acc); acc = fmaf(xp[p][7],  w1.w, acc);
    acc = fmaf(xp[p][8],  w2.x, acc); acc = fmaf(xp[p][9],  w2.y, acc);
    acc = fmaf(xp[p][10], w2.z, acc); acc = fmaf(xp[p][11], w2.w, acc);
    acc = fmaf(xp[p][12], w3.x, acc); acc = fmaf(xp[p][13], w3.y, acc);
    acc = fmaf(xp[p][14], w3.z, acc); acc = fmaf(xp[p][15], w3.w, acc);
    qkv[m][p][c] = acc;
  }
  __syncthreads();

  #pragma unroll
  for (int r = 0; r < 4; ++r){
    const int p = tid >> 4, qi = tid & 15;
    const float4* qa = (const float4*)&qkv[0][p][r * 32];
    const float4* ka = (const float4*)&qkv[1][qi][r * 32];
    float acc = 0.f;
    #pragma unroll
    for (int cc = 0; cc < 8; ++cc){
      float4 qv = qa[cc], kv = ka[cc];
      acc = fmaf(qv.x, kv.x, acc); acc = fmaf(qv.y, kv.y, acc);
      acc = fmaf(qv.z, kv.z, acc); acc = fmaf(qv.w, kv.w, acc);
    }
    am[r][p][qi] = acc * (1.0f / 16.0f);
  }
  __syncthreads();

  if (tid < 64){
    const int h = tid >> 4, p = tid & 15;
    float m = -1e30f;
    #pragma unroll
    for (int qi = 0; qi < 16; ++qi) m = fmaxf(m, am[h][p][qi]);
    float s = 0.f;
    #pragma unroll
    for (int qi = 0; qi < 16; ++qi){
      float e = __expf(am[h][p][qi] - m);
      am[h][p][qi] = e; s += e;
    }
    float inv = 1.0f / s;
    #pragma unroll
    for (int qi = 0; qi < 16; ++qi) am[h][p][qi] *= inv;
  }
  __syncthreads();

  #pragma unroll
  for (int r = 0; r < 8; ++r){
    const int h = r >> 1;
    const int p = ((r & 1) << 3) + (tid >> 5);
    const int c = tid & 31;
    float acc = 0.f;
    #pragma unroll
    for (int qi = 0; qi < 16; ++qi)
      acc = fmaf(am[h][p][qi], qkv[2][qi][h * 32 + c], acc);
    oc2[p][h * 32 + c] = acc;
  }
  __syncthreads();

  {
    const int p = tid >> 4, jj = tid & 15;
    const float4* wr = (const float4*)(Wlo + jj * 128);
    const float4* ov = (const float4*)&oc2[p][0];
    float acc = blo[jj];
    #pragma unroll
    for (int u = 0; u < 32; ++u){
      float4 w = wr[u], o4 = ov[u];
      acc = fmaf(o4.x, w.x, acc); acc = fmaf(o4.y, w.y, acc);
      acc = fmaf(o4.z, w.z, acc); acc = fmaf(o4.w, w.w, acc);
    }
    y[n * 256 + tid] = acc;
  }
}

// ---------------------------------------------------------------------------
// K5: out = LN(y @ Wlout^T + blout + x1). wave-per-token butterfly GEMV.
// ---------------------------------------------------------------------------
__global__ __launch_bounds__(512) void k_out(const float* __restrict__ y,
                                             const float* __restrict__ Wlout,
                                             const float* __restrict__ blout,
                                             const float* __restrict__ x1,
                                             float* __restrict__ out)
{
  const int lane = threadIdx.x & 63;
  const int n    = blockIdx.x * 8 + (threadIdx.x >> 6);
  const float4 yf = *(const float4*)(y + n * 256 + lane * 4);

  float outl[4];
  #pragma unroll
  for (int seg = 0; seg < 4; ++seg){
    float keep = 0.f;
    #pragma unroll 4
    for (int dd = 0; dd < 64; ++dd){
      const float4 w = *(const float4*)(Wlout + (seg * 64 + dd) * 256 + lane * 4);
      float acc;
      acc = yf.x * w.x; acc = fmaf(yf.y, w.y, acc);
      acc = fmaf(yf.z, w.z, acc); acc = fmaf(yf.w, w.w, acc);
      acc += __shfl_xor(acc, 32); acc += __shfl_xor(acc, 16); acc += __shfl_xor(acc, 8);
      acc += __shfl_xor(acc, 4);  acc += __shfl_xor(acc, 2);  acc += __shfl_xor(acc, 1);
      keep = (lane == dd) ? acc : keep;
    }
    outl[seg] = keep;
  }

  float v0 = outl[0] + blout[lane]       + x1[n*256 + lane];
  float v1 = outl[1] + blout[64 + lane]  + x1[n*256 + 64 + lane];
  float v2 = outl[2] + blout[128 + lane] + x1[n*256 + 128 + lane];
  float v3 = outl[3] + blout[192 + lane] + x1[n*256 + 192 + lane];
  float sum = v0 + v1 + v2 + v3;
  #pragma unroll
  for (int mk = 32; mk >= 1; mk >>= 1) sum += __shfl_xor(sum, mk);
  float mean = sum * (1.0f / 256.0f);
  float e0 = v0 - mean, e1 = v1 - mean, e2 = v2 - mean, e3 = v3 - mean;
  float sq = e0*e0 + e1*e1 + e2*e2 + e3*e3;
  #pragma unroll
  for (int mk = 32; mk >= 1; mk >>= 1) sq += __shfl_xor(sq, mk);
  float inv = rsqrtf(sq * (1.0f / 255.0f));
  out[n*256 + lane]       = e0 * inv;
  out[n*256 + 64 + lane]  = e1 * inv;
  out[n*256 + 128 + lane] = e2 * inv;
  out[n*256 + 192 + lane] = e3 * inv;
}

// ---------------------------------------------------------------------------
extern "C" void kernel_launch(void* const* d_in, const int* in_sizes, int n_in,
                              void* d_out, int out_size, void* d_ws, size_t ws_size,
                              hipStream_t stream)
{
  const float* x     = (const float*)d_in[0];
  const float* Wq    = (const float*)d_in[1];
  const float* bq    = (const float*)d_in[2];
  const float* Wk    = (const float*)d_in[3];
  const float* bk    = (const float*)d_in[4];
  const float* Wv    = (const float*)d_in[5];
  const float* bv    = (const float*)d_in[6];
  const float* Wlin1 = (const float*)d_in[7];
  const float* blin1 = (const float*)d_in[8];
  const float* Wqc   = (const float*)d_in[9];
  const float* bqc   = (const float*)d_in[10];
  const float* Wkc   = (const float*)d_in[11];
  const float* bkc   = (const float*)d_in[12];
  const float* Wvl   = (const float*)d_in[13];
  const float* bvl   = (const float*)d_in[14];
  const float* Wlo   = (const float*)d_in[15];
  const float* blo   = (const float*)d_in[16];
  const float* Wlout = (const float*)d_in[17];
  const float* blout = (const float*)d_in[18];
  float* out = (float*)d_out;

  // workspace layout (bytes):
  // 0         Qw bf16 [128][512][256]   (33.55 MB)
  // 33554432  Kw bf16                   (33.55 MB)
  // 67108864  Vw bf16                   (33.55 MB)
  // 100663296 Ow bf16 [16384][1024]     (33.55 MB)
  // 134217728 Vt bf16 [128][256][512]   (33.55 MB)  -- aliases x1+y (Vt dead
  //           x1 f32 [16384][256] @134217728, y f32 @150994944   after attn)
  // 167772160 WqkvT f32 [256][3072]     ( 3.15 MB)  total ~171 MB
  char* w = (char*)d_ws;
  unsigned short* Qw = (unsigned short*)w;
  unsigned short* Kw = Qw + 16777216;
  unsigned short* Vw = Kw + 16777216;
  unsigned short* Ow = Vw + 16777216;
  unsigned short* Vtw = (unsigned short*)(w + 134217728);
  float* x1    = (float*)(w + 134217728);
  float* y     = x1 + 4194304;
  float* WqkvT = y + 4194304;

  hipFuncSetAttribute((const void*)k_attn, hipFuncAttributeMaxDynamicSharedMemorySize, 147456);

  k_prep <<<3072, 256, 0, stream>>>(Wq, Wk, Wv, WqkvT);
  k_qkv  <<<1024, 256, 0, stream>>>(x, WqkvT, bq, bk, bv, Qw, Kw, Vw);
  k_vt   <<<dim3(8, 4, 128), 256, 0, stream>>>(Vw, Vtw);
  k_attn <<<dim3(4, 128), 512, 147456, stream>>>(Qw, Kw, Vtw, Ow);
  k_lin1 <<<2048, 512, 0, stream>>>(Ow, Wlin1, blin1, x, x1);
  k_patch<<<16384, 256, 0, stream>>>(x1, Wqc, bqc, Wkc, bkc, Wvl, bvl, Wlo, blo, y);
  k_out  <<<2048, 512, 0, stream>>>(y, Wlout, blout, x1, out);
}

// Round 4
// 1010.487 us; speedup vs baseline: 4.6816x; 2.7661x over previous
//
#include <hip/hip_runtime.h>
#include <hip/hip_bf16.h>
#include <math.h>

// ---- problem constants ----
// bs=32, S=512, D=256, HS=4 heads (head dim = D = 256!), NT = 16384 tokens
// patch: NP=16 patches x P=16, CC=128, HP=4 heads x CE=32

typedef __attribute__((ext_vector_type(8))) short bf16x8;
typedef __attribute__((ext_vector_type(4))) float f32x4;

__device__ __forceinline__ float bf_lo(unsigned u){ return __uint_as_float(u << 16); }
__device__ __forceinline__ float bf_hi(unsigned u){ return __uint_as_float(u & 0xFFFF0000u); }
__device__ __forceinline__ unsigned short f2bf(float f){
  unsigned u = __float_as_uint(f);
  return (unsigned short)((u + 0x7FFFu + ((u >> 16) & 1u)) >> 16);   // RNE
}
__device__ __forceinline__ unsigned pack2bf(float a, float b){
  return (unsigned)f2bf(a) | ((unsigned)f2bf(b) << 16);
}
// async 16B global->LDS (dest = wave-uniform base + lane*16)
__device__ __forceinline__ void gld16(const void* g, void* l){
  __builtin_amdgcn_global_load_lds((const __attribute__((address_space(1))) void*)g,
                                   (__attribute__((address_space(3))) void*)l, 16, 0, 0);
}

// ---------------------------------------------------------------------------
// cvt: f32 -> bf16, vectorized x4
// ---------------------------------------------------------------------------
__global__ __launch_bounds__(256) void k_cvt(const float* __restrict__ src,
                                             unsigned short* __restrict__ dst, int n4)
{
  int i = blockIdx.x * 256 + threadIdx.x;
  if (i < n4){
    float4 v = ((const float4*)src)[i];
    ushort4 o;
    o.x = f2bf(v.x); o.y = f2bf(v.y); o.z = f2bf(v.z); o.w = f2bf(v.w);
    ((ushort4*)dst)[i] = o;
  }
}

// ---------------------------------------------------------------------------
// k_gemm: C[M,128-tile] = A[M,K](bf16) . W[N,K](bf16)^T, 128x128 block tile,
// 4 waves (64x64/wave), BK=64, dbuf global_load_lds w/ pre-swizzled source.
// EPI 0: bias + scatter to QKV bf16 [bh][s][d].  EPI 1: bias + resid -> f32.
// ---------------------------------------------------------------------------
template<int EPI>
__global__ __launch_bounds__(256) void k_gemm(
    const unsigned short* __restrict__ A,   // [M,K] bf16
    const unsigned short* __restrict__ W,   // [N,K] bf16
    const float* __restrict__ b0,
    const float* __restrict__ b1,
    const float* __restrict__ b2,
    const float* __restrict__ resid,        // EPI==1: f32 [M,256]
    void* __restrict__ outp,                // EPI==0: Qw base; EPI==1: f32 out
    unsigned short* __restrict__ Kw_,
    unsigned short* __restrict__ Vw_,
    int K)
{
  extern __shared__ char sm[];
  const int tid = threadIdx.x;
  const int wid = tid >> 6, lane = tid & 63;
  const int g = lane >> 4, li = lane & 15;
  const int wm = wid >> 1, wn = wid & 1;
  const int m0 = blockIdx.x << 7, n0 = blockIdx.y << 7;

  const unsigned short* Ab = A + (size_t)m0 * K;
  const unsigned short* Wb = W + (size_t)n0 * K;

  auto stage = [&](char* dst, const unsigned short* src, int k0){
    #pragma unroll
    for (int r = 0; r < 4; ++r){
      int row = (r << 5) + (tid >> 3);
      int cb  = (tid & 7) << 4;
      int cbs = cb ^ ((row & 7) << 4);
      gld16(src + row * K + k0 + (cbs >> 1), dst + (r << 12) + (wid << 10));
    }
  };

  f32x4 acc[4][4];
  #pragma unroll
  for (int mf = 0; mf < 4; ++mf)
    #pragma unroll
    for (int nf = 0; nf < 4; ++nf) acc[mf][nf] = (f32x4){0.f,0.f,0.f,0.f};

  const int nk = K >> 6;
  stage(sm, Ab, 0); stage(sm + 32768, Wb, 0);
  for (int kt = 0; kt < nk; ++kt){
    char* Acur = (kt & 1) ? (sm + 16384) : sm;
    char* Wcur = (kt & 1) ? (sm + 49152) : (sm + 32768);
    if (kt + 1 < nk){
      char* Anxt = (kt & 1) ? sm : (sm + 16384);
      char* Wnxt = (kt & 1) ? (sm + 32768) : (sm + 49152);
      stage(Anxt, Ab, (kt + 1) << 6);
      stage(Wnxt, Wb, (kt + 1) << 6);
    }
    __syncthreads();
    bf16x8 af[2][4], wf[2][4];
    #pragma unroll
    for (int kk = 0; kk < 2; ++kk){
      #pragma unroll
      for (int mf = 0; mf < 4; ++mf){
        int row  = (wm << 6) + (mf << 4) + li;
        int colb = ((kk << 6) + (g << 4)) ^ ((row & 7) << 4);
        af[kk][mf] = *(const bf16x8*)(Acur + (row << 7) + colb);
      }
      #pragma unroll
      for (int nf = 0; nf < 4; ++nf){
        int row  = (wn << 6) + (nf << 4) + li;
        int colb = ((kk << 6) + (g << 4)) ^ ((row & 7) << 4);
        wf[kk][nf] = *(const bf16x8*)(Wcur + (row << 7) + colb);
      }
    }
    #pragma unroll
    for (int kk = 0; kk < 2; ++kk)
      #pragma unroll
      for (int mf = 0; mf < 4; ++mf)
        #pragma unroll
        for (int nf = 0; nf < 4; ++nf)
          acc[mf][nf] = __builtin_amdgcn_mfma_f32_16x16x32_bf16(af[kk][mf], wf[kk][nf], acc[mf][nf], 0, 0, 0);
    __syncthreads();
  }

  // lane holds C[m0 + wm*64 + mf*16 + g*4 + r][n0 + wn*64 + nf*16 + li]
  if (EPI == 0){
    const int chunk = n0 >> 10;
    const float* bias = (chunk == 0) ? b0 : (chunk == 1 ? b1 : b2);
    unsigned short* dst = (chunk == 0) ? (unsigned short*)outp : (chunk == 1 ? Kw_ : Vw_);
    const int nq0 = n0 & 1023;
    const int h = nq0 >> 8;                 // uniform per block
    #pragma unroll
    for (int nf = 0; nf < 4; ++nf){
      const int nq = nq0 + (wn << 6) + (nf << 4) + li;
      const int d = nq & 255;
      const float bv = bias[nq];
      #pragma unroll
      for (int mf = 0; mf < 4; ++mf){
        const int mbase = m0 + (wm << 6) + (mf << 4) + (g << 2);
        #pragma unroll
        for (int r = 0; r < 4; ++r){
          const int m = mbase + r;
          const int b = m >> 9, s = m & 511;
          dst[(size_t)((((b << 2) + h) << 9) + s) * 256 + d] = f2bf(acc[mf][nf][r] + bv);
        }
      }
    }
  } else {
    float* op = (float*)outp;
    #pragma unroll
    for (int nf = 0; nf < 4; ++nf){
      const int n = n0 + (wn << 6) + (nf << 4) + li;
      const float bv = b0[n];
      #pragma unroll
      for (int mf = 0; mf < 4; ++mf){
        const int mbase = m0 + (wm << 6) + (mf << 4) + (g << 2);
        #pragma unroll
        for (int r = 0; r < 4; ++r){
          const int m = mbase + r;
          op[(size_t)m * 256 + n] = acc[mf][nf][r] + bv + resid[(size_t)m * 256 + n];
        }
      }
    }
  }
}

// ---------------------------------------------------------------------------
// k_ln: LN (mean/std, ddof=1, no eps) over rows of 256. wave per token.
// ---------------------------------------------------------------------------
__global__ __launch_bounds__(512) void k_ln(const float* __restrict__ src,
                                            float* __restrict__ dst)
{
  const int lane = threadIdx.x & 63;
  const int n    = blockIdx.x * 8 + (threadIdx.x >> 6);
  float4 v = *(const float4*)(src + (size_t)n * 256 + lane * 4);
  float sum = v.x + v.y + v.z + v.w;
  #pragma unroll
  for (int mk = 32; mk >= 1; mk >>= 1) sum += __shfl_xor(sum, mk);
  float mean = sum * (1.0f / 256.0f);
  float4 e; e.x = v.x - mean; e.y = v.y - mean; e.z = v.z - mean; e.w = v.w - mean;
  float sq = e.x*e.x + e.y*e.y + e.z*e.z + e.w*e.w;
  #pragma unroll
  for (int mk = 32; mk >= 1; mk >>= 1) sq += __shfl_xor(sq, mk);
  float inv = rsqrtf(sq * (1.0f / 255.0f));
  e.x *= inv; e.y *= inv; e.z *= inv; e.w *= inv;
  *(float4*)(dst + (size_t)n * 256 + lane * 4) = e;
}

// ---------------------------------------------------------------------------
// K1b: V transpose per bh: Vt[bh][d][s] from Vw[bh][s][d], 64x64 tiles.
// ---------------------------------------------------------------------------
__global__ __launch_bounds__(256) void k_vt(const unsigned short* __restrict__ Vw,
                                            unsigned short* __restrict__ Vt)
{
  __shared__ unsigned short tile[64][72];
  const int tid = threadIdx.x;
  const int s0 = blockIdx.x << 6, d0 = blockIdx.y << 6, bh = blockIdx.z;
  const unsigned short* src = Vw + (bh * 512 + s0) * 256 + d0;
  #pragma unroll
  for (int p = 0; p < 2; ++p){
    int idx = p * 256 + tid;
    int sl = idx >> 3, db = (idx & 7) * 8;
    *(uint4*)&tile[sl][db] = *(const uint4*)(src + sl * 256 + db);
  }
  __syncthreads();
  #pragma unroll
  for (int p = 0; p < 2; ++p){
    int idx = p * 256 + tid;
    int dl = idx >> 3, sb = (idx & 7) * 8, m = idx & 7;
    unsigned short r[8] __attribute__((aligned(16)));
    #pragma unroll
    for (int k = 0; k < 8; ++k){
      int kk = (k + m) & 7;
      r[kk] = tile[sb + kk][dl];
    }
    *(uint4*)(Vt + (bh * 256 + d0 + dl) * 512 + s0 + sb) = *(uint4*)r;
  }
}

// ---------------------------------------------------------------------------
// K2: MFMA flash attention. 8 waves x 16 q-rows = 128 q/block, grid (4,128).
// ---------------------------------------------------------------------------
__global__ __launch_bounds__(512) void k_attn(const unsigned short* __restrict__ Qw,
                                              const unsigned short* __restrict__ Kw,
                                              const unsigned short* __restrict__ Vt,
                                              unsigned short* __restrict__ Ow)
{
  extern __shared__ char smem[];
  const int tid  = threadIdx.x;
  const int wid  = tid >> 6, lane = tid & 63;
  const int g    = lane >> 4, li = lane & 15, l7 = lane & 7;
  const int bh   = blockIdx.y;
  const int sblk = blockIdx.x << 7;
  const int q0   = sblk + (wid << 4);

  char* const PB = smem + 131072 + (wid << 11);

  auto stageK = [&](char* kbuf, int t0){
    const unsigned short* base = Kw + ((bh << 9) + t0 + (wid << 3)) * 256;
    char* dst = kbuf + (wid << 12);
    #pragma unroll
    for (int c = 0; c < 4; ++c){
      int r  = (c << 1) + (lane >> 5);
      int cs = ((((lane & 31) << 4) ^ (r << 4)) >> 1);
      gld16(base + (r << 8) + cs, dst + (c << 10));
    }
  };
  auto stageV = [&](char* vbuf, int t0){
    const unsigned short* base = Vt + (bh * 256 + wid * 32) * 512 + t0;
    char* dst = vbuf + (wid << 12);
    int cs = ((lane & 7) ^ (lane >> 3)) << 3;
    #pragma unroll
    for (int c = 0; c < 4; ++c){
      int r = (c << 3) + (lane >> 3);
      gld16(base + (r << 9) + cs, dst + (c << 10));
    }
  };

  stageK(smem, 0);
  stageV(smem + 32768, 0);

  bf16x8 qf[8];
  {
    const unsigned short* qp = Qw + ((bh << 9) + q0 + li) * 256 + (g << 3);
    #pragma unroll
    for (int kk = 0; kk < 8; ++kk)
      qf[kk] = *(const bf16x8*)(qp + (kk << 5));
  }

  f32x4 o[16];
  #pragma unroll
  for (int df = 0; df < 16; ++df) o[df] = (f32x4){0.f,0.f,0.f,0.f};
  float mrun = -3.0e38f, lrun = 0.f;

  __syncthreads();
  const float inv256 = 1.0f / 256.0f;

  for (int t = 0; t < 8; ++t){
    char* kb = (t & 1) ? (smem + 65536) : smem;
    char* vb = (t & 1) ? (smem + 98304) : (smem + 32768);
    if (t < 7){
      char* kn = (t & 1) ? smem : (smem + 65536);
      char* vn = (t & 1) ? (smem + 32768) : (smem + 98304);
      stageK(kn, (t + 1) << 6);
      stageV(vn, (t + 1) << 6);
    }

    f32x4 st[4];
    #pragma unroll
    for (int tf = 0; tf < 4; ++tf){
      st[tf] = (f32x4){0.f,0.f,0.f,0.f};
      const int rowb = ((tf << 4) + li) << 9;
      #pragma unroll
      for (int kk = 0; kk < 8; ++kk){
        const int colb = ((kk << 6) + (g << 4)) ^ (l7 << 4);
        bf16x8 kf = *(const bf16x8*)(kb + rowb + colb);
        st[tf] = __builtin_amdgcn_mfma_f32_16x16x32_bf16(kf, qf[kk], st[tf], 0, 0, 0);
      }
    }

    float s[16];
    #pragma unroll
    for (int tf = 0; tf < 4; ++tf){
      s[tf*4+0] = st[tf].x * inv256; s[tf*4+1] = st[tf].y * inv256;
      s[tf*4+2] = st[tf].z * inv256; s[tf*4+3] = st[tf].w * inv256;
    }
    float pmax = s[0];
    #pragma unroll
    for (int i = 1; i < 16; ++i) pmax = fmaxf(pmax, s[i]);
    pmax = fmaxf(pmax, __shfl_xor(pmax, 16));
    pmax = fmaxf(pmax, __shfl_xor(pmax, 32));
    float mnew = fmaxf(mrun, pmax);
    float corr = __expf(mrun - mnew);
    float psum = 0.f;
    #pragma unroll
    for (int i = 0; i < 16; ++i){ s[i] = __expf(s[i] - mnew); psum += s[i]; }
    psum += __shfl_xor(psum, 16);
    psum += __shfl_xor(psum, 32);
    lrun = lrun * corr + psum;
    if (!__all(mnew == mrun)){
      #pragma unroll
      for (int df = 0; df < 16; ++df) o[df] *= corr;
    }
    mrun = mnew;

    #pragma unroll
    for (int tf = 0; tf < 4; ++tf){
      uint2 pk; pk.x = pack2bf(s[tf*4+0], s[tf*4+1]); pk.y = pack2bf(s[tf*4+2], s[tf*4+3]);
      const int addr = (li << 7) + (((tf << 5) + (g << 3)) ^ (l7 << 4));
      *(uint2*)(PB + addr) = pk;
    }
    __asm__ volatile("s_waitcnt lgkmcnt(0)" ::: "memory");
    __builtin_amdgcn_sched_barrier(0);

    #pragma unroll
    for (int tt = 0; tt < 2; ++tt){
      const int colb = ((tt << 6) + (g << 4)) ^ (l7 << 4);
      bf16x8 pb = *(const bf16x8*)(PB + (li << 7) + colb);
      #pragma unroll
      for (int df = 0; df < 16; ++df){
        bf16x8 va = *(const bf16x8*)(vb + (((df << 4) + li) << 7) + colb);
        o[df] = __builtin_amdgcn_mfma_f32_16x16x32_bf16(va, pb, o[df], 0, 0, 0);
      }
    }
    __syncthreads();
  }

  float inv = 1.0f / lrun;
  #pragma unroll
  for (int df = 0; df < 16; ++df) o[df] *= inv;

  char* const OT = smem + (wid << 14);
  #pragma unroll
  for (int df = 0; df < 16; ++df){
    uint2 pk; pk.x = pack2bf(o[df].x, o[df].y); pk.y = pack2bf(o[df].z, o[df].w);
    const int addr = (li << 9) + (((df << 5) + (g << 3)) ^ (l7 << 4));
    *(uint2*)(OT + addr) = pk;
  }
  __asm__ volatile("s_waitcnt lgkmcnt(0)" ::: "memory");
  __builtin_amdgcn_sched_barrier(0);
  const int b = bh >> 2, h = bh & 3;
  #pragma unroll
  for (int p = 0; p < 8; ++p){
    const int row  = (p << 1) + (lane >> 5);
    const int colb = ((lane & 31) << 4) ^ ((row & 7) << 4);
    uint4 vv = *(const uint4*)(OT + (row << 9) + colb);
    const int d0 = (lane & 31) << 3;
    *(uint4*)(Ow + ((b << 9) + sblk + (wid << 4) + row) * 1024 + (h << 8) + d0) = vv;
  }
}

// ---------------------------------------------------------------------------
// K4: CNN patch attention per token (block = 1 token, 256 thr, all LDS).
// y (bf16) = (oc2 @ Wlo^T + blo) flattened, pre-Wlout.
// ---------------------------------------------------------------------------
__global__ __launch_bounds__(256) void k_patch(const float* __restrict__ x1,
    const float* __restrict__ Wqc, const float* __restrict__ bqc,
    const float* __restrict__ Wkc, const float* __restrict__ bkc,
    const float* __restrict__ Wvl, const float* __restrict__ bvl,
    const float* __restrict__ Wlo, const float* __restrict__ blo,
    unsigned short* __restrict__ yb)
{
  __shared__ float xp[16][17];
  __shared__ float qkv[3][16][132];
  __shared__ float am[4][16][17];
  __shared__ float oc2[16][132];
  const int tid = threadIdx.x;
  const int n   = blockIdx.x;

  xp[tid >> 4][tid & 15] = x1[(size_t)n * 256 + tid];
  __syncthreads();

  #pragma unroll
  for (int r = 0; r < 24; ++r){
    const int m = r >> 3;
    const int p = ((r & 7) << 1) + (tid >> 7);
    const int c = tid & 127;
    const float* W  = (m == 0) ? Wqc : (m == 1 ? Wkc : Wvl);
    const float* bb = (m == 0) ? bqc : (m == 1 ? bkc : bvl);
    const float4* wr = (const float4*)(W + c * 16);
    const float4 w0 = wr[0], w1 = wr[1], w2 = wr[2], w3 = wr[3];
    float acc = bb[c];
    acc = fmaf(xp[p][0],  w0.x, acc); acc = fmaf(xp[p][1],  w0.y, acc);
    acc = fmaf(xp[p][2],  w0.z, acc); acc = fmaf(xp[p][3],  w0.w, acc);
    acc = fmaf(xp[p][4],  w1.x, acc); acc = fmaf(xp[p][5],  w1.y, acc);
    acc = fmaf(xp[p][6],  w1.z, acc); acc = fmaf(xp[p][7],  w1.w, acc);
    acc = fmaf(xp[p][8],  w2.x, acc); acc = fmaf(xp[p][9],  w2.y, acc);
    acc = fmaf(xp[p][10], w2.z, acc); acc = fmaf(xp[p][11], w2.w, acc);
    acc = fmaf(xp[p][12], w3.x, acc); acc = fmaf(xp[p][13], w3.y, acc);
    acc = fmaf(xp[p][14], w3.z, acc); acc = fmaf(xp[p][15], w3.w, acc);
    qkv[m][p][c] = acc;
  }
  __syncthreads();

  #pragma unroll
  for (int r = 0; r < 4; ++r){
    const int p = tid >> 4, qi = tid & 15;
    const float4* qa = (const float4*)&qkv[0][p][r * 32];
    const float4* ka = (const float4*)&qkv[1][qi][r * 32];
    float acc = 0.f;
    #pragma unroll
    for (int cc = 0; cc < 8; ++cc){
      float4 qv = qa[cc], kv = ka[cc];
      acc = fmaf(qv.x, kv.x, acc); acc = fmaf(qv.y, kv.y, acc);
      acc = fmaf(qv.z, kv.z, acc); acc = fmaf(qv.w, kv.w, acc);
    }
    am[r][p][qi] = acc * (1.0f / 16.0f);
  }
  __syncthreads();

  if (tid < 64){
    const int h = tid >> 4, p = tid & 15;
    float m = -1e30f;
    #pragma unroll
    for (int qi = 0; qi < 16; ++qi) m = fmaxf(m, am[h][p][qi]);
    float s = 0.f;
    #pragma unroll
    for (int qi = 0; qi < 16; ++qi){
      float e = __expf(am[h][p][qi] - m);
      am[h][p][qi] = e; s += e;
    }
    float inv = 1.0f / s;
    #pragma unroll
    for (int qi = 0; qi < 16; ++qi) am[h][p][qi] *= inv;
  }
  __syncthreads();

  #pragma unroll
  for (int r = 0; r < 8; ++r){
    const int h = r >> 1;
    const int p = ((r & 1) << 3) + (tid >> 5);
    const int c = tid & 31;
    float acc = 0.f;
    #pragma unroll
    for (int qi = 0; qi < 16; ++qi)
      acc = fmaf(am[h][p][qi], qkv[2][qi][h * 32 + c], acc);
    oc2[p][h * 32 + c] = acc;
  }
  __syncthreads();

  {
    const int p = tid >> 4, jj = tid & 15;
    const float4* wr = (const float4*)(Wlo + jj * 128);
    const float4* ov = (const float4*)&oc2[p][0];
    float acc = blo[jj];
    #pragma unroll
    for (int u = 0; u < 32; ++u){
      float4 w = wr[u], o4 = ov[u];
      acc = fmaf(o4.x, w.x, acc); acc = fmaf(o4.y, w.y, acc);
      acc = fmaf(o4.z, w.z, acc); acc = fmaf(o4.w, w.w, acc);
    }
    yb[(size_t)n * 256 + tid] = f2bf(acc);
  }
}

// ---------------------------------------------------------------------------
extern "C" void kernel_launch(void* const* d_in, const int* in_sizes, int n_in,
                              void* d_out, int out_size, void* d_ws, size_t ws_size,
                              hipStream_t stream)
{
  const float* x     = (const float*)d_in[0];
  const float* Wq    = (const float*)d_in[1];
  const float* bq    = (const float*)d_in[2];
  const float* Wk    = (const float*)d_in[3];
  const float* bk    = (const float*)d_in[4];
  const float* Wv    = (const float*)d_in[5];
  const float* bv    = (const float*)d_in[6];
  const float* Wlin1 = (const float*)d_in[7];
  const float* blin1 = (const float*)d_in[8];
  const float* Wqc   = (const float*)d_in[9];
  const float* bqc   = (const float*)d_in[10];
  const float* Wkc   = (const float*)d_in[11];
  const float* bkc   = (const float*)d_in[12];
  const float* Wvl   = (const float*)d_in[13];
  const float* bvl   = (const float*)d_in[14];
  const float* Wlo   = (const float*)d_in[15];
  const float* blo   = (const float*)d_in[16];
  const float* Wlout = (const float*)d_in[17];
  const float* blout = (const float*)d_in[18];
  float* out = (float*)d_out;

  // workspace layout (bytes), with aliasing (lifetimes disjoint):
  // 0         Qw bf16 [128][512][256] 33.5M   | after attn: yb bf16 [16384][256] 8.4M
  // 33554432  Kw bf16 33.5M
  // 67108864  Vw bf16 33.5M
  // 100663296 xb bf16 [16384][256] 8.4M (pre-attn) | Ow bf16 [16384][1024] 33.5M
  // 134217728 Vt bf16 33.5M (attn) | x1raw f32 16.8M -> outraw f32 16.8M
  // 150994944   (2nd half of Vt)   | x1 f32 16.8M (ln1 .. end)
  // 167772160 Wqkvb bf16 [3072][256] 1.57M
  // 169345024 Wlin1b bf16 [256][1024] 0.52M
  // 169869312 Wloutb bf16 [256][256] 0.13M    total ~170.0M
  char* w = (char*)d_ws;
  unsigned short* Qw  = (unsigned short*)w;
  unsigned short* yb  = (unsigned short*)w;
  unsigned short* Kw  = (unsigned short*)(w + 33554432);
  unsigned short* Vw  = (unsigned short*)(w + 67108864);
  unsigned short* xb  = (unsigned short*)(w + 100663296);
  unsigned short* Ow  = (unsigned short*)(w + 100663296);
  unsigned short* Vtw = (unsigned short*)(w + 134217728);
  float* x1raw  = (float*)(w + 134217728);
  float* outraw = (float*)(w + 134217728);
  float* x1     = (float*)(w + 150994944);
  unsigned short* Wqkvb  = (unsigned short*)(w + 167772160);
  unsigned short* Wlin1b = (unsigned short*)(w + 169345024);
  unsigned short* Wloutb = (unsigned short*)(w + 169869312);

  hipFuncSetAttribute((const void*)k_attn, hipFuncAttributeMaxDynamicSharedMemorySize, 147456);
  hipFuncSetAttribute((const void*)k_gemm<0>, hipFuncAttributeMaxDynamicSharedMemorySize, 65536);
  hipFuncSetAttribute((const void*)k_gemm<1>, hipFuncAttributeMaxDynamicSharedMemorySize, 65536);

  // ---- prep: dtype conversions (weights are [N,K] row-major already) ----
  k_cvt<<<4096, 256, 0, stream>>>(x, xb, 1048576);
  k_cvt<<<256, 256, 0, stream>>>(Wq, Wqkvb, 65536);
  k_cvt<<<256, 256, 0, stream>>>(Wk, Wqkvb + 262144, 65536);
  k_cvt<<<256, 256, 0, stream>>>(Wv, Wqkvb + 524288, 65536);
  k_cvt<<<256, 256, 0, stream>>>(Wlin1, Wlin1b, 65536);
  k_cvt<<<64, 256, 0, stream>>>(Wlout, Wloutb, 16384);

  // ---- QKV projection (MFMA GEMM, scatter epilogue) ----
  k_gemm<0><<<dim3(128, 24), 256, 65536, stream>>>(xb, Wqkvb, bq, bk, bv,
                                                   nullptr, Qw, Kw, Vw, 256);
  k_vt  <<<dim3(8, 4, 128), 256, 0, stream>>>(Vw, Vtw);
  k_attn<<<dim3(4, 128), 512, 147456, stream>>>(Qw, Kw, Vtw, Ow);

  // ---- lin1 + LN ----
  k_gemm<1><<<dim3(128, 2), 256, 65536, stream>>>(Ow, Wlin1b, blin1, nullptr, nullptr,
                                                  x, x1raw, nullptr, nullptr, 1024);
  k_ln<<<2048, 512, 0, stream>>>(x1raw, x1);

  // ---- patch attention ----
  k_patch<<<16384, 256, 0, stream>>>(x1, Wqc, bqc, Wkc, bkc, Wvl, bvl, Wlo, blo, yb);

  // ---- Wlout + LN ----
  k_gemm<1><<<dim3(128, 2), 256, 65536, stream>>>(yb, Wloutb, blout, nullptr, nullptr,
                                                  x1, outraw, nullptr, nullptr, 256);
  k_ln<<<2048, 512, 0, stream>>>(outraw, out);
}

// Round 5
// 241.247 us; speedup vs baseline: 19.6093x; 4.1886x over previous
//
#include <hip/hip_runtime.h>
#include <hip/hip_bf16.h>
#include <math.h>

// ---- problem constants ----
// bs=32, S=512, D=256, HS=4 heads (head dim = D = 256!), NT = 16384 tokens
// patch: NP=16 patches x P=16, CC=128, HP=4 heads x CE=32

typedef __attribute__((ext_vector_type(8))) short bf16x8;
typedef __attribute__((ext_vector_type(4))) float f32x4;

__device__ __forceinline__ float bf_lo(unsigned u){ return __uint_as_float(u << 16); }
__device__ __forceinline__ float bf_hi(unsigned u){ return __uint_as_float(u & 0xFFFF0000u); }
__device__ __forceinline__ unsigned short f2bf(float f){
  unsigned u = __float_as_uint(f);
  return (unsigned short)((u + 0x7FFFu + ((u >> 16) & 1u)) >> 16);   // RNE
}
__device__ __forceinline__ unsigned pack2bf(float a, float b){
  return (unsigned)f2bf(a) | ((unsigned)f2bf(b) << 16);
}
__device__ __forceinline__ bf16x8 pack8(float a0,float a1,float a2,float a3,
                                        float a4,float a5,float a6,float a7){
  union { bf16x8 v; unsigned u[4]; } t;
  t.u[0]=pack2bf(a0,a1); t.u[1]=pack2bf(a2,a3);
  t.u[2]=pack2bf(a4,a5); t.u[3]=pack2bf(a6,a7);
  return t.v;
}
// async 16B global->LDS (dest = wave-uniform base + lane*16)
__device__ __forceinline__ void gld16(const void* g, void* l){
  __builtin_amdgcn_global_load_lds((const __attribute__((address_space(1))) void*)g,
                                   (__attribute__((address_space(3))) void*)l, 16, 0, 0);
}

// ---------------------------------------------------------------------------
// cvt: f32 -> bf16, vectorized x4
// ---------------------------------------------------------------------------
__global__ __launch_bounds__(256) void k_cvt(const float* __restrict__ src,
                                             unsigned short* __restrict__ dst, int n4)
{
  int i = blockIdx.x * 256 + threadIdx.x;
  if (i < n4){
    float4 v = ((const float4*)src)[i];
    ushort4 o;
    o.x = f2bf(v.x); o.y = f2bf(v.y); o.z = f2bf(v.z); o.w = f2bf(v.w);
    ((ushort4*)dst)[i] = o;
  }
}

// ---------------------------------------------------------------------------
// k_packw: pre-pack patch weights into per-lane MFMA B-fragment layout.
// chunks 0..23: Wqc/Wkc/Wvl (8 chunks of 16 cols each, K=16 zero-padded to 32)
// chunks 24..27: Wlo^T (4 K-chunks of 32, N=16)
// ---------------------------------------------------------------------------
__global__ __launch_bounds__(256) void k_packw(
    const float* __restrict__ Wqc, const float* __restrict__ Wkc,
    const float* __restrict__ Wvl, const float* __restrict__ Wlo,
    unsigned short* __restrict__ Wp)
{
  int it = blockIdx.x * 256 + threadIdx.x;     // 28*64 = 1792 items
  if (it >= 1792) return;
  int ch = it >> 6, lane = it & 63;
  int g = lane >> 4, li = lane & 15;
  unsigned short o[8];
  if (ch < 24){
    int m = ch >> 3, nc = ch & 7;
    const float* W = (m == 0) ? Wqc : (m == 1 ? Wkc : Wvl);
    int c = nc * 16 + li;
    #pragma unroll
    for (int j = 0; j < 8; ++j){
      int k = g * 8 + j;
      o[j] = (k < 16) ? f2bf(W[c * 16 + k]) : (unsigned short)0;
    }
  } else {
    int kc = ch - 24;
    #pragma unroll
    for (int j = 0; j < 8; ++j){
      int k = kc * 32 + g * 8 + j;
      o[j] = f2bf(Wlo[li * 128 + k]);
    }
  }
  #pragma unroll
  for (int j = 0; j < 8; ++j) Wp[it * 8 + j] = o[j];
}

// ---------------------------------------------------------------------------
// k_gemm: C[M,128-tile] = A[M,K](bf16) . W[N,K](bf16)^T, 128x128 block tile,
// 4 waves (64x64/wave), BK=64, dbuf global_load_lds w/ pre-swizzled source.
// EPI 0: bias + scatter to QKV bf16 [bh][s][d].  EPI 1: bias + resid -> f32.
// ---------------------------------------------------------------------------
template<int EPI>
__global__ __launch_bounds__(256) void k_gemm(
    const unsigned short* __restrict__ A,   // [M,K] bf16
    const unsigned short* __restrict__ W,   // [N,K] bf16
    const float* __restrict__ b0,
    const float* __restrict__ b1,
    const float* __restrict__ b2,
    const float* __restrict__ resid,        // EPI==1: f32 [M,256]
    void* __restrict__ outp,                // EPI==0: Qw base; EPI==1: f32 out
    unsigned short* __restrict__ Kw_,
    unsigned short* __restrict__ Vw_,
    int K)
{
  extern __shared__ char sm[];
  const int tid = threadIdx.x;
  const int wid = tid >> 6, lane = tid & 63;
  const int g = lane >> 4, li = lane & 15;
  const int wm = wid >> 1, wn = wid & 1;
  const int m0 = blockIdx.x << 7, n0 = blockIdx.y << 7;

  const unsigned short* Ab = A + (size_t)m0 * K;
  const unsigned short* Wb = W + (size_t)n0 * K;

  auto stage = [&](char* dst, const unsigned short* src, int k0){
    #pragma unroll
    for (int r = 0; r < 4; ++r){
      int row = (r << 5) + (tid >> 3);
      int cb  = (tid & 7) << 4;
      int cbs = cb ^ ((row & 7) << 4);
      gld16(src + row * K + k0 + (cbs >> 1), dst + (r << 12) + (wid << 10));
    }
  };

  f32x4 acc[4][4];
  #pragma unroll
  for (int mf = 0; mf < 4; ++mf)
    #pragma unroll
    for (int nf = 0; nf < 4; ++nf) acc[mf][nf] = (f32x4){0.f,0.f,0.f,0.f};

  const int nk = K >> 6;
  stage(sm, Ab, 0); stage(sm + 32768, Wb, 0);
  for (int kt = 0; kt < nk; ++kt){
    char* Acur = (kt & 1) ? (sm + 16384) : sm;
    char* Wcur = (kt & 1) ? (sm + 49152) : (sm + 32768);
    if (kt + 1 < nk){
      char* Anxt = (kt & 1) ? sm : (sm + 16384);
      char* Wnxt = (kt & 1) ? (sm + 32768) : (sm + 49152);
      stage(Anxt, Ab, (kt + 1) << 6);
      stage(Wnxt, Wb, (kt + 1) << 6);
    }
    __syncthreads();
    bf16x8 af[2][4], wf[2][4];
    #pragma unroll
    for (int kk = 0; kk < 2; ++kk){
      #pragma unroll
      for (int mf = 0; mf < 4; ++mf){
        int row  = (wm << 6) + (mf << 4) + li;
        int colb = ((kk << 6) + (g << 4)) ^ ((row & 7) << 4);
        af[kk][mf] = *(const bf16x8*)(Acur + (row << 7) + colb);
      }
      #pragma unroll
      for (int nf = 0; nf < 4; ++nf){
        int row  = (wn << 6) + (nf << 4) + li;
        int colb = ((kk << 6) + (g << 4)) ^ ((row & 7) << 4);
        wf[kk][nf] = *(const bf16x8*)(Wcur + (row << 7) + colb);
      }
    }
    #pragma unroll
    for (int kk = 0; kk < 2; ++kk)
      #pragma unroll
      for (int mf = 0; mf < 4; ++mf)
        #pragma unroll
        for (int nf = 0; nf < 4; ++nf)
          acc[mf][nf] = __builtin_amdgcn_mfma_f32_16x16x32_bf16(af[kk][mf], wf[kk][nf], acc[mf][nf], 0, 0, 0);
    __syncthreads();
  }

  // lane holds C[m0 + wm*64 + mf*16 + g*4 + r][n0 + wn*64 + nf*16 + li]
  if (EPI == 0){
    const int chunk = n0 >> 10;
    const float* bias = (chunk == 0) ? b0 : (chunk == 1 ? b1 : b2);
    unsigned short* dst = (chunk == 0) ? (unsigned short*)outp : (chunk == 1 ? Kw_ : Vw_);
    const int nq0 = n0 & 1023;
    const int h = nq0 >> 8;                 // uniform per block
    #pragma unroll
    for (int nf = 0; nf < 4; ++nf){
      const int nq = nq0 + (wn << 6) + (nf << 4) + li;
      const int d = nq & 255;
      const float bv = bias[nq];
      #pragma unroll
      for (int mf = 0; mf < 4; ++mf){
        const int mbase = m0 + (wm << 6) + (mf << 4) + (g << 2);
        #pragma unroll
        for (int r = 0; r < 4; ++r){
          const int m = mbase + r;
          const int b = m >> 9, s = m & 511;
          dst[(size_t)((((b << 2) + h) << 9) + s) * 256 + d] = f2bf(acc[mf][nf][r] + bv);
        }
      }
    }
  } else {
    float* op = (float*)outp;
    #pragma unroll
    for (int nf = 0; nf < 4; ++nf){
      const int n = n0 + (wn << 6) + (nf << 4) + li;
      const float bv = b0[n];
      #pragma unroll
      for (int mf = 0; mf < 4; ++mf){
        const int mbase = m0 + (wm << 6) + (mf << 4) + (g << 2);
        #pragma unroll
        for (int r = 0; r < 4; ++r){
          const int m = mbase + r;
          op[(size_t)m * 256 + n] = acc[mf][nf][r] + bv + resid[(size_t)m * 256 + n];
        }
      }
    }
  }
}

// ---------------------------------------------------------------------------
// k_ln: LN (mean/std, ddof=1, no eps) over rows of 256. wave per token.
// ---------------------------------------------------------------------------
__global__ __launch_bounds__(512) void k_ln(const float* __restrict__ src,
                                            float* __restrict__ dst)
{
  const int lane = threadIdx.x & 63;
  const int n    = blockIdx.x * 8 + (threadIdx.x >> 6);
  float4 v = *(const float4*)(src + (size_t)n * 256 + lane * 4);
  float sum = v.x + v.y + v.z + v.w;
  #pragma unroll
  for (int mk = 32; mk >= 1; mk >>= 1) sum += __shfl_xor(sum, mk);
  float mean = sum * (1.0f / 256.0f);
  float4 e; e.x = v.x - mean; e.y = v.y - mean; e.z = v.z - mean; e.w = v.w - mean;
  float sq = e.x*e.x + e.y*e.y + e.z*e.z + e.w*e.w;
  #pragma unroll
  for (int mk = 32; mk >= 1; mk >>= 1) sq += __shfl_xor(sq, mk);
  float inv = rsqrtf(sq * (1.0f / 255.0f));
  e.x *= inv; e.y *= inv; e.z *= inv; e.w *= inv;
  *(float4*)(dst + (size_t)n * 256 + lane * 4) = e;
}

// ---------------------------------------------------------------------------
// K1b: V transpose per bh: Vt[bh][d][s] from Vw[bh][s][d], 64x64 tiles.
// ---------------------------------------------------------------------------
__global__ __launch_bounds__(256) void k_vt(const unsigned short* __restrict__ Vw,
                                            unsigned short* __restrict__ Vt)
{
  __shared__ unsigned short tile[64][72];
  const int tid = threadIdx.x;
  const int s0 = blockIdx.x << 6, d0 = blockIdx.y << 6, bh = blockIdx.z;
  const unsigned short* src = Vw + (bh * 512 + s0) * 256 + d0;
  #pragma unroll
  for (int p = 0; p < 2; ++p){
    int idx = p * 256 + tid;
    int sl = idx >> 3, db = (idx & 7) * 8;
    *(uint4*)&tile[sl][db] = *(const uint4*)(src + sl * 256 + db);
  }
  __syncthreads();
  #pragma unroll
  for (int p = 0; p < 2; ++p){
    int idx = p * 256 + tid;
    int dl = idx >> 3, sb = (idx & 7) * 8, m = idx & 7;
    unsigned short r[8] __attribute__((aligned(16)));
    #pragma unroll
    for (int k = 0; k < 8; ++k){
      int kk = (k + m) & 7;
      r[kk] = tile[sb + kk][dl];
    }
    *(uint4*)(Vt + (bh * 256 + d0 + dl) * 512 + s0 + sb) = *(uint4*)r;
  }
}

// ---------------------------------------------------------------------------
// K2: MFMA flash attention. 8 waves x 16 q-rows = 128 q/block, grid (4,128).
// ---------------------------------------------------------------------------
__global__ __launch_bounds__(512) void k_attn(const unsigned short* __restrict__ Qw,
                                              const unsigned short* __restrict__ Kw,
                                              const unsigned short* __restrict__ Vt,
                                              unsigned short* __restrict__ Ow)
{
  extern __shared__ char smem[];
  const int tid  = threadIdx.x;
  const int wid  = tid >> 6, lane = tid & 63;
  const int g    = lane >> 4, li = lane & 15, l7 = lane & 7;
  const int bh   = blockIdx.y;
  const int sblk = blockIdx.x << 7;
  const int q0   = sblk + (wid << 4);

  char* const PB = smem + 131072 + (wid << 11);

  auto stageK = [&](char* kbuf, int t0){
    const unsigned short* base = Kw + ((bh << 9) + t0 + (wid << 3)) * 256;
    char* dst = kbuf + (wid << 12);
    #pragma unroll
    for (int c = 0; c < 4; ++c){
      int r  = (c << 1) + (lane >> 5);
      int cs = ((((lane & 31) << 4) ^ (r << 4)) >> 1);
      gld16(base + (r << 8) + cs, dst + (c << 10));
    }
  };
  auto stageV = [&](char* vbuf, int t0){
    const unsigned short* base = Vt + (bh * 256 + wid * 32) * 512 + t0;
    char* dst = vbuf + (wid << 12);
    int cs = ((lane & 7) ^ (lane >> 3)) << 3;
    #pragma unroll
    for (int c = 0; c < 4; ++c){
      int r = (c << 3) + (lane >> 3);
      gld16(base + (r << 9) + cs, dst + (c << 10));
    }
  };

  stageK(smem, 0);
  stageV(smem + 32768, 0);

  bf16x8 qf[8];
  {
    const unsigned short* qp = Qw + ((bh << 9) + q0 + li) * 256 + (g << 3);
    #pragma unroll
    for (int kk = 0; kk < 8; ++kk)
      qf[kk] = *(const bf16x8*)(qp + (kk << 5));
  }

  f32x4 o[16];
  #pragma unroll
  for (int df = 0; df < 16; ++df) o[df] = (f32x4){0.f,0.f,0.f,0.f};
  float mrun = -3.0e38f, lrun = 0.f;

  __syncthreads();
  const float inv256 = 1.0f / 256.0f;

  for (int t = 0; t < 8; ++t){
    char* kb = (t & 1) ? (smem + 65536) : smem;
    char* vb = (t & 1) ? (smem + 98304) : (smem + 32768);
    if (t < 7){
      char* kn = (t & 1) ? smem : (smem + 65536);
      char* vn = (t & 1) ? (smem + 32768) : (smem + 98304);
      stageK(kn, (t + 1) << 6);
      stageV(vn, (t + 1) << 6);
    }

    f32x4 st[4];
    #pragma unroll
    for (int tf = 0; tf < 4; ++tf){
      st[tf] = (f32x4){0.f,0.f,0.f,0.f};
      const int rowb = ((tf << 4) + li) << 9;
      #pragma unroll
      for (int kk = 0; kk < 8; ++kk){
        const int colb = ((kk << 6) + (g << 4)) ^ (l7 << 4);
        bf16x8 kf = *(const bf16x8*)(kb + rowb + colb);
        st[tf] = __builtin_amdgcn_mfma_f32_16x16x32_bf16(kf, qf[kk], st[tf], 0, 0, 0);
      }
    }

    float s[16];
    #pragma unroll
    for (int tf = 0; tf < 4; ++tf){
      s[tf*4+0] = st[tf].x * inv256; s[tf*4+1] = st[tf].y * inv256;
      s[tf*4+2] = st[tf].z * inv256; s[tf*4+3] = st[tf].w * inv256;
    }
    float pmax = s[0];
    #pragma unroll
    for (int i = 1; i < 16; ++i) pmax = fmaxf(pmax, s[i]);
    pmax = fmaxf(pmax, __shfl_xor(pmax, 16));
    pmax = fmaxf(pmax, __shfl_xor(pmax, 32));
    float mnew = fmaxf(mrun, pmax);
    float corr = __expf(mrun - mnew);
    float psum = 0.f;
    #pragma unroll
    for (int i = 0; i < 16; ++i){ s[i] = __expf(s[i] - mnew); psum += s[i]; }
    psum += __shfl_xor(psum, 16);
    psum += __shfl_xor(psum, 32);
    lrun = lrun * corr + psum;
    if (!__all(mnew == mrun)){
      #pragma unroll
      for (int df = 0; df < 16; ++df) o[df] *= corr;
    }
    mrun = mnew;

    #pragma unroll
    for (int tf = 0; tf < 4; ++tf){
      uint2 pk; pk.x = pack2bf(s[tf*4+0], s[tf*4+1]); pk.y = pack2bf(s[tf*4+2], s[tf*4+3]);
      const int addr = (li << 7) + (((tf << 5) + (g << 3)) ^ (l7 << 4));
      *(uint2*)(PB + addr) = pk;
    }
    __asm__ volatile("s_waitcnt lgkmcnt(0)" ::: "memory");
    __builtin_amdgcn_sched_barrier(0);

    #pragma unroll
    for (int tt = 0; tt < 2; ++tt){
      const int colb = ((tt << 6) + (g << 4)) ^ (l7 << 4);
      bf16x8 pb = *(const bf16x8*)(PB + (li << 7) + colb);
      #pragma unroll
      for (int df = 0; df < 16; ++df){
        bf16x8 va = *(const bf16x8*)(vb + (((df << 4) + li) << 7) + colb);
        o[df] = __builtin_amdgcn_mfma_f32_16x16x32_bf16(va, pb, o[df], 0, 0, 0);
      }
    }
    __syncthreads();
  }

  float inv = 1.0f / lrun;
  #pragma unroll
  for (int df = 0; df < 16; ++df) o[df] *= inv;

  char* const OT = smem + (wid << 14);
  #pragma unroll
  for (int df = 0; df < 16; ++df){
    uint2 pk; pk.x = pack2bf(o[df].x, o[df].y); pk.y = pack2bf(o[df].z, o[df].w);
    const int addr = (li << 9) + (((df << 5) + (g << 3)) ^ (l7 << 4));
    *(uint2*)(OT + addr) = pk;
  }
  __asm__ volatile("s_waitcnt lgkmcnt(0)" ::: "memory");
  __builtin_amdgcn_sched_barrier(0);
  const int b = bh >> 2, h = bh & 3;
  #pragma unroll
  for (int p = 0; p < 8; ++p){
    const int row  = (p << 1) + (lane >> 5);
    const int colb = ((lane & 31) << 4) ^ ((row & 7) << 4);
    uint4 vv = *(const uint4*)(OT + (row << 9) + colb);
    const int d0 = (lane & 31) << 3;
    *(uint4*)(Ow + ((b << 9) + sblk + (wid << 4) + row) * 1024 + (h << 8) + d0) = vv;
  }
}

// ---------------------------------------------------------------------------
// K4: patch attention, wave-per-token MFMA, no __syncthreads.
// 4 waves/block (4 tokens), 16KB LDS per wave:
//   QB [16p][256B swz] / KB same / VT [128c][48B] / PB [16p][80B]
// ---------------------------------------------------------------------------
__global__ __launch_bounds__(256) void k_patch2(
    const float* __restrict__ x1,
    const unsigned short* __restrict__ Wp,
    const float* __restrict__ bqc, const float* __restrict__ bkc,
    const float* __restrict__ bvl, const float* __restrict__ blo,
    unsigned short* __restrict__ yb)
{
  extern __shared__ char lds[];
  const int tid = threadIdx.x;
  const int wid = tid >> 6, lane = tid & 63;
  const int g = lane >> 4, li = lane & 15;
  const int n = (blockIdx.x << 2) + wid;

  char* const QB = lds + (wid << 14);
  char* const KB = QB + 4096;
  char* const VB = QB + 8192;
  char* const PB = QB + 14336;
  const int swz = (li & 7) << 4;
  const bf16x8 zf = (bf16x8){0,0,0,0,0,0,0,0};

  // ---- XP A-frag (K=16 pad 32): lanes g<2 load 8 f32, else zero ----
  bf16x8 xf = zf;
  if (g < 2){
    const float* xr = x1 + (size_t)n * 256 + li * 16 + g * 8;
    float4 a = *(const float4*)xr;
    float4 b = *(const float4*)(xr + 4);
    xf = pack8(a.x,a.y,a.z,a.w, b.x,b.y,b.z,b.w);
  }

  // ---- QKVc: 24 mfmas; Q,K -> swizzled [p][c] rows; V -> VT[c][q] ----
  #pragma unroll
  for (int m = 0; m < 3; ++m){
    const float* bias = (m == 0) ? bqc : ((m == 1) ? bkc : bvl);
    #pragma unroll
    for (int nc = 0; nc < 8; ++nc){
      bf16x8 wf = *(const bf16x8*)(Wp + ((((m << 3) + nc) << 6) + lane) * 8);
      f32x4 c = __builtin_amdgcn_mfma_f32_16x16x32_bf16(xf, wf, (f32x4){0,0,0,0}, 0, 0, 0);
      float bv = bias[(nc << 4) + li];
      if (m < 2){
        char* B = (m == 0) ? QB : KB;
        #pragma unroll
        for (int r = 0; r < 4; ++r){
          int p = (g << 2) + r;
          *(unsigned short*)(B + (p << 8) + (((((nc << 4) + li) << 1)) ^ ((p & 7) << 4))) = f2bf(c[r] + bv);
        }
      } else {
        int cc = (nc << 4) + li;
        *(unsigned*)(VB + cc * 48 + (g << 3))     = pack2bf(c[0] + bv, c[1] + bv);
        *(unsigned*)(VB + cc * 48 + (g << 3) + 4) = pack2bf(c[2] + bv, c[3] + bv);
      }
    }
  }
  __asm__ volatile("s_waitcnt lgkmcnt(0)" ::: "memory");
  __builtin_amdgcn_sched_barrier(0);

  // ---- per head: S^T = K_h.Q_h^T (1 mfma), softmax in-lane, PV (2 mfmas) ----
  f32x4 of[8];
  #pragma unroll
  for (int i = 0; i < 8; ++i) of[i] = (f32x4){0,0,0,0};

  #pragma unroll
  for (int h = 0; h < 4; ++h){
    const int cb = (h << 6) + (g << 4);
    bf16x8 kf = *(const bf16x8*)(KB + (li << 8) + (cb ^ swz));
    bf16x8 qf = *(const bf16x8*)(QB + (li << 8) + (cb ^ swz));
    f32x4 st = __builtin_amdgcn_mfma_f32_16x16x32_bf16(kf, qf, (f32x4){0,0,0,0}, 0, 0, 0);
    // lane (g,li): st[r] = S[p=li][q=g*4+r] / 16; softmax over q
    float s0 = st[0]*0.0625f, s1 = st[1]*0.0625f, s2 = st[2]*0.0625f, s3 = st[3]*0.0625f;
    float mx = fmaxf(fmaxf(s0, s1), fmaxf(s2, s3));
    mx = fmaxf(mx, __shfl_xor(mx, 16));
    mx = fmaxf(mx, __shfl_xor(mx, 32));
    float e0 = __expf(s0-mx), e1 = __expf(s1-mx), e2 = __expf(s2-mx), e3 = __expf(s3-mx);
    float ss = e0 + e1 + e2 + e3;
    ss += __shfl_xor(ss, 16);
    ss += __shfl_xor(ss, 32);
    float inv = 1.0f / ss;
    e0 *= inv; e1 *= inv; e2 *= inv; e3 *= inv;
    // P[p=li][q=g*4+r] -> PB rows of 80B
    *(unsigned*)(PB + li * 80 + (g << 3))     = pack2bf(e0, e1);
    *(unsigned*)(PB + li * 80 + (g << 3) + 4) = pack2bf(e2, e3);
    __asm__ volatile("s_waitcnt lgkmcnt(0)" ::: "memory");
    __builtin_amdgcn_sched_barrier(0);
    bf16x8 pf = zf;
    if (g < 2) pf = *(const bf16x8*)(PB + li * 80 + (g << 4));
    #pragma unroll
    for (int t = 0; t < 2; ++t){
      bf16x8 vf = zf;
      if (g < 2) vf = *(const bf16x8*)(VB + ((h << 5) + (t << 4) + li) * 48 + (g << 4));
      of[(h << 1) + t] = __builtin_amdgcn_mfma_f32_16x16x32_bf16(pf, vf, of[(h << 1) + t], 0, 0, 0);
    }
  }

  // ---- oc -> QB (reuse), then y = oc @ Wlo^T + blo (4 mfmas) ----
  #pragma unroll
  for (int h = 0; h < 4; ++h)
    #pragma unroll
    for (int t = 0; t < 2; ++t){
      f32x4 c = of[(h << 1) + t];
      int cc = (h << 5) + (t << 4) + li;
      #pragma unroll
      for (int r = 0; r < 4; ++r){
        int p = (g << 2) + r;
        *(unsigned short*)(QB + (p << 8) + ((cc << 1) ^ ((p & 7) << 4))) = f2bf(c[r]);
      }
    }
  __asm__ volatile("s_waitcnt lgkmcnt(0)" ::: "memory");
  __builtin_amdgcn_sched_barrier(0);

  f32x4 y = (f32x4){0,0,0,0};
  #pragma unroll
  for (int kc = 0; kc < 4; ++kc){
    bf16x8 af = *(const bf16x8*)(QB + (li << 8) + ((((kc << 6) + (g << 4))) ^ swz));
    bf16x8 wf = *(const bf16x8*)(Wp + (((24 + kc) << 6) + lane) * 8);
    y = __builtin_amdgcn_mfma_f32_16x16x32_bf16(af, wf, y, 0, 0, 0);
  }
  float bv = blo[li];
  unsigned short* yr = yb + (size_t)n * 256 + li;
  #pragma unroll
  for (int r = 0; r < 4; ++r)
    yr[((g << 2) + r) << 4] = f2bf(y[r] + bv);
}

// ---------------------------------------------------------------------------
extern "C" void kernel_launch(void* const* d_in, const int* in_sizes, int n_in,
                              void* d_out, int out_size, void* d_ws, size_t ws_size,
                              hipStream_t stream)
{
  const float* x     = (const float*)d_in[0];
  const float* Wq    = (const float*)d_in[1];
  const float* bq    = (const float*)d_in[2];
  const float* Wk    = (const float*)d_in[3];
  const float* bk    = (const float*)d_in[4];
  const float* Wv    = (const float*)d_in[5];
  const float* bv    = (const float*)d_in[6];
  const float* Wlin1 = (const float*)d_in[7];
  const float* blin1 = (const float*)d_in[8];
  const float* Wqc   = (const float*)d_in[9];
  const float* bqc   = (const float*)d_in[10];
  const float* Wkc   = (const float*)d_in[11];
  const float* bkc   = (const float*)d_in[12];
  const float* Wvl   = (const float*)d_in[13];
  const float* bvl   = (const float*)d_in[14];
  const float* Wlo   = (const float*)d_in[15];
  const float* blo   = (const float*)d_in[16];
  const float* Wlout = (const float*)d_in[17];
  const float* blout = (const float*)d_in[18];
  float* out = (float*)d_out;

  // workspace layout (bytes), aliased (lifetimes disjoint):
  // 0         Qw bf16 33.5M  | after attn: yb bf16 8.4M
  // 33554432  Kw bf16 33.5M
  // 67108864  Vw bf16 33.5M
  // 100663296 xb bf16 8.4M (pre-attn) | Ow bf16 33.5M
  // 134217728 Vt bf16 33.5M (attn) | x1raw f32 -> outraw f32 16.8M
  // 150994944 (Vt 2nd half)        | x1 f32 16.8M
  // 167772160 Wqkvb bf16 1.57M
  // 169345024 Wlin1b bf16 0.52M
  // 169869312 Wloutb bf16 0.13M
  // 170000384 Wp bf16 packed patch frags 28.7K     total ~170.03M
  char* w = (char*)d_ws;
  unsigned short* Qw  = (unsigned short*)w;
  unsigned short* yb  = (unsigned short*)w;
  unsigned short* Kw  = (unsigned short*)(w + 33554432);
  unsigned short* Vw  = (unsigned short*)(w + 67108864);
  unsigned short* xb  = (unsigned short*)(w + 100663296);
  unsigned short* Ow  = (unsigned short*)(w + 100663296);
  unsigned short* Vtw = (unsigned short*)(w + 134217728);
  float* x1raw  = (float*)(w + 134217728);
  float* outraw = (float*)(w + 134217728);
  float* x1     = (float*)(w + 150994944);
  unsigned short* Wqkvb  = (unsigned short*)(w + 167772160);
  unsigned short* Wlin1b = (unsigned short*)(w + 169345024);
  unsigned short* Wloutb = (unsigned short*)(w + 169869312);
  unsigned short* Wp     = (unsigned short*)(w + 170000384);

  hipFuncSetAttribute((const void*)k_attn, hipFuncAttributeMaxDynamicSharedMemorySize, 147456);
  hipFuncSetAttribute((const void*)k_gemm<0>, hipFuncAttributeMaxDynamicSharedMemorySize, 65536);
  hipFuncSetAttribute((const void*)k_gemm<1>, hipFuncAttributeMaxDynamicSharedMemorySize, 65536);
  hipFuncSetAttribute((const void*)k_patch2, hipFuncAttributeMaxDynamicSharedMemorySize, 65536);

  // ---- prep: dtype conversions + patch weight fragment packing ----
  k_cvt<<<4096, 256, 0, stream>>>(x, xb, 1048576);
  k_cvt<<<256, 256, 0, stream>>>(Wq, Wqkvb, 65536);
  k_cvt<<<256, 256, 0, stream>>>(Wk, Wqkvb + 262144, 65536);
  k_cvt<<<256, 256, 0, stream>>>(Wv, Wqkvb + 524288, 65536);
  k_cvt<<<256, 256, 0, stream>>>(Wlin1, Wlin1b, 65536);
  k_cvt<<<64, 256, 0, stream>>>(Wlout, Wloutb, 16384);
  k_packw<<<7, 256, 0, stream>>>(Wqc, Wkc, Wvl, Wlo, Wp);

  // ---- QKV projection (MFMA GEMM, scatter epilogue) ----
  k_gemm<0><<<dim3(128, 24), 256, 65536, stream>>>(xb, Wqkvb, bq, bk, bv,
                                                   nullptr, Qw, Kw, Vw, 256);
  k_vt  <<<dim3(8, 4, 128), 256, 0, stream>>>(Vw, Vtw);
  k_attn<<<dim3(4, 128), 512, 147456, stream>>>(Qw, Kw, Vtw, Ow);

  // ---- lin1 + LN ----
  k_gemm<1><<<dim3(128, 2), 256, 65536, stream>>>(Ow, Wlin1b, blin1, nullptr, nullptr,
                                                  x, x1raw, nullptr, nullptr, 1024);
  k_ln<<<2048, 512, 0, stream>>>(x1raw, x1);

  // ---- patch attention (wave-per-token MFMA) ----
  k_patch2<<<4096, 256, 65536, stream>>>(x1, Wp, bqc, bkc, bvl, blo, yb);

  // ---- Wlout + LN ----
  k_gemm<1><<<dim3(128, 2), 256, 65536, stream>>>(yb, Wloutb, blout, nullptr, nullptr,
                                                  x1, outraw, nullptr, nullptr, 256);
  k_ln<<<2048, 512, 0, stream>>>(outraw, out);
}